// Round 13
// baseline (375.568 us; speedup 1.0000x reference)
//
#include <hip/hip_runtime.h>
#include <math.h>
#include <float.h>

#define D 128

typedef short short8 __attribute__((ext_vector_type(8)));
typedef float f32x4 __attribute__((ext_vector_type(4)));

__device__ __forceinline__ unsigned int bf16r(float f) {
    unsigned int u = __float_as_uint(f);
    return (u + 0x7fffu + ((u >> 16) & 1u)) >> 16;   // RNE
}
__device__ __forceinline__ float bf2f(unsigned int lo16) {
    return __uint_as_float(lo16 << 16);
}

// ---------------- fused prep: count_rank | gemm0_raw | wprep | bounds ----------------
// count_rank is atomic-transaction-bound (VALUBusy 0.3%): hide layer-0 GEMM
// (m_raw = x @ W0, dinv applied later) plus wprep and bounds under its shadow.
#define GBM0 64
__global__ __launch_bounds__(256) void prep_fused(
    const int* __restrict__ dst, int* __restrict__ cnt, int* __restrict__ rank, int E,
    const float* __restrict__ x, unsigned short* __restrict__ mraw, int n,
    const float* __restrict__ W, const float* __restrict__ b,
    const float* __restrict__ gamma, const float* __restrict__ beta,
    const float* __restrict__ rmean, const float* __restrict__ rvar,
    unsigned short* __restrict__ Wt, float* __restrict__ sc, float* __restrict__ sh, int L_,
    const int* __restrict__ batch, int* __restrict__ gstart, int G,
    int cb, int gb, int wb) {
    __shared__ short Wl[D * 136];
    const int blk = blockIdx.x;
    const int tid = threadIdx.x;
    if (blk < cb) {
        // ---- count + rank (batch-4) ----
        int base = (blk * 256 + tid) * 4;
        if (base + 4 <= E) {
            int4 d = *(const int4*)&dst[base];
            int r0 = atomicAdd(&cnt[d.x], 1);
            int r1 = atomicAdd(&cnt[d.y], 1);
            int r2 = atomicAdd(&cnt[d.z], 1);
            int r3 = atomicAdd(&cnt[d.w], 1);
            *(int4*)&rank[base] = make_int4(r0, r1, r2, r3);
        } else if (base < E) {
            for (int e = base; e < E; ++e) rank[e] = atomicAdd(&cnt[dst[e]], 1);
        }
    } else if (blk < cb + gb) {
        // ---- layer-0 GEMM, un-scaled: mraw[r][:] = x[r][:] @ W0 ----
        // stage W0^T into LDS: coalesced f32 read, transposed bf16 write
#pragma unroll
        for (int i = 0; i < 64; ++i) {
            int t = i * 256 + tid;               // 0..16383
            int k = t >> 7, r = t & 127;         // W0[k][r]
            Wl[r * 136 + k] = (short)bf16r(W[t]);
        }
        __syncthreads();

        const int row0 = (blk - cb) * GBM0;
        const int wid = tid >> 6;                // 4 waves -> 16 rows each
        const int lane = tid & 63;
        const int lr = lane & 15;
        const int lg = lane >> 4;
        const int grow = row0 + wid * 16 + lr;
        const bool valid = grow < n;

        f32x4 acc[8];
#pragma unroll
        for (int fc = 0; fc < 8; ++fc) acc[fc] = (f32x4){0.f, 0.f, 0.f, 0.f};

#pragma unroll
        for (int ks = 0; ks < 4; ++ks) {
            int kb = ks * 32 + lg * 8;
            float4 va = make_float4(0.f, 0.f, 0.f, 0.f);
            float4 vb = make_float4(0.f, 0.f, 0.f, 0.f);
            if (valid) {
                va = *(const float4*)&x[(size_t)grow * D + kb];
                vb = *(const float4*)&x[(size_t)grow * D + kb + 4];
            }
            uint4 pk;
            pk.x = bf16r(va.x) | (bf16r(va.y) << 16);
            pk.y = bf16r(va.z) | (bf16r(va.w) << 16);
            pk.z = bf16r(vb.x) | (bf16r(vb.y) << 16);
            pk.w = bf16r(vb.z) | (bf16r(vb.w) << 16);
            short8 y = *(short8*)&pk;
#pragma unroll
            for (int fc = 0; fc < 8; ++fc) {
                short8 xf = *(const short8*)&Wl[(fc * 16 + lr) * 136 + kb];
                acc[fc] = __builtin_amdgcn_mfma_f32_16x16x32_bf16(xf, y, acc[fc], 0, 0, 0);
            }
        }

        if (valid) {
#pragma unroll
            for (int fc = 0; fc < 8; ++fc) {
                int gcol = fc * 16 + lg * 4;
                uint2 pk;
                pk.x = bf16r(acc[fc][0]) | (bf16r(acc[fc][1]) << 16);
                pk.y = bf16r(acc[fc][2]) | (bf16r(acc[fc][3]) << 16);
                *(uint2*)&mraw[(size_t)grow * D + gcol] = pk;
            }
        }
    } else if (blk < cb + gb + wb) {
        // ---- wprep: W transpose -> bf16, BN fold ----
        int t = (blk - cb - gb) * 256 + tid;
        int total = L_ * D * D;
        if (t < total) {
            int l = t / (D * D), rem = t % (D * D);
            int r = rem >> 7, k = rem & 127;      // Wt[l][r][k] = W[l][k][r]
            Wt[t] = (unsigned short)bf16r(W[l * D * D + k * D + r]);
        }
        if (t < L_ * D) {
            float inv = rsqrtf(rvar[t] + 1e-5f);
            float s = inv * gamma[t];
            sc[t] = s;
            sh[t] = (b[t] - rmean[t]) * s + beta[t];
        }
    } else {
        // ---- bounds: graph start offsets from sorted batch ----
        int i = (blk - cb - gb - wb) * 256 + tid;
        if (i >= n) return;
        int g = batch[i];
        int gp = (i == 0) ? -1 : batch[i - 1];
        for (int gg = gp + 1; gg <= g; ++gg) gstart[gg] = i;
        if (i == n - 1) for (int gg = g + 1; gg <= G; ++gg) gstart[gg] = n;
    }
}

// ---------------- scans (block-local exclusive; consumers add aux[idx>>10]) ----------------

__global__ void scan1(const int* __restrict__ cnt, int* __restrict__ rp, int* __restrict__ aux,
                      float* __restrict__ dinv, int n) {
    __shared__ int sh[256];
    int tid = threadIdx.x;
    int base = blockIdx.x * 1024 + tid * 4;
    int v[4]; int s = 0;
#pragma unroll
    for (int i = 0; i < 4; i++) {
        int idx = base + i;
        int t = (idx < n) ? cnt[idx] : 0;
        if (idx < n) dinv[idx] = rsqrtf((float)t + 1.0f);   // +1 self-loop
        v[i] = s; s += t;
    }
    sh[tid] = s; __syncthreads();
    for (int off = 1; off < 256; off <<= 1) {
        int t = (tid >= off) ? sh[tid - off] : 0;
        __syncthreads();
        sh[tid] += t;
        __syncthreads();
    }
    int excl = sh[tid] - s;
#pragma unroll
    for (int i = 0; i < 4; i++) { int idx = base + i; if (idx < n) rp[idx] = excl + v[i]; }
    if (tid == 255) aux[blockIdx.x] = sh[255];
}

__global__ void scan2(int* aux, int nb) {
    __shared__ int sh[256];
    int tid = threadIdx.x;
    int v = (tid < nb) ? aux[tid] : 0;
    sh[tid] = v; __syncthreads();
    for (int off = 1; off < 256; off <<= 1) {
        int t = (tid >= off) ? sh[tid - off] : 0;
        __syncthreads();
        sh[tid] += t;
        __syncthreads();
    }
    if (tid < nb) aux[tid] = sh[tid] - v;   // exclusive
}

// ---------------- fused: fill | scale m_raw by dinv ----------------
// fill is latency-bound: the streaming dinv-scale of layer-0 m rides free.
__global__ __launch_bounds__(256) void fill_scale(
    const int* __restrict__ src, const int* __restrict__ dst,
    const int* __restrict__ rp, const int* __restrict__ aux,
    const int* __restrict__ rank, int* __restrict__ csr, int E,
    unsigned int* __restrict__ M, const float* __restrict__ dinv, int n,
    int fb) {
    const int blk = blockIdx.x;
    const int tid = threadIdx.x;
    if (blk < fb) {
        // ---- fill: atomic-free scatter, batch-4 ----
        int base = (blk * 256 + tid) * 4;
        if (base + 4 <= E) {
            int4 d = *(const int4*)&dst[base];
            int4 s = *(const int4*)&src[base];
            int4 r = *(const int4*)&rank[base];
            int p0 = rp[d.x] + aux[d.x >> 10];
            int p1 = rp[d.y] + aux[d.y >> 10];
            int p2 = rp[d.z] + aux[d.z >> 10];
            int p3 = rp[d.w] + aux[d.w >> 10];
            csr[p0 + r.x] = s.x;
            csr[p1 + r.y] = s.y;
            csr[p2 + r.z] = s.z;
            csr[p3 + r.w] = s.w;
        } else if (base < E) {
            for (int e = base; e < E; ++e)
                csr[rp[dst[e]] + aux[dst[e] >> 10] + rank[e]] = src[e];
        }
    } else {
        // ---- scale: M[row][:] *= dinv[row] (in-place bf16 RMW, uint4/thread) ----
        int t = (blk - fb) * 256 + tid;          // uint4 index
        int total4 = n * 16;                      // 64 uints/row = 16 uint4
        if (t >= total4) return;
        int row = t >> 4;
        float di = dinv[row];
        uint4 v = *(uint4*)&M[(size_t)t * 4];
        uint4 o;
        o.x = bf16r(bf2f(v.x & 0xffffu) * di) | (bf16r(bf2f(v.x >> 16) * di) << 16);
        o.y = bf16r(bf2f(v.y & 0xffffu) * di) | (bf16r(bf2f(v.y >> 16) * di) << 16);
        o.z = bf16r(bf2f(v.z & 0xffffu) * di) | (bf16r(bf2f(v.z >> 16) * di) << 16);
        o.w = bf16r(bf2f(v.w & 0xffffu) * di) | (bf16r(bf2f(v.w >> 16) * di) << 16);
        *(uint4*)&M[(size_t)t * 4] = o;
    }
}

// ---------------- standalone staged GEMM (layers 1,2) ----------------
#define GBM 128
__global__ __launch_bounds__(512) void gemm_mfma(const unsigned short* __restrict__ hin,
                                                 const unsigned short* __restrict__ Wt,
                                                 const float* __restrict__ dinv,
                                                 unsigned short* __restrict__ mout, int n) {
    __shared__ short Ah[GBM * 136];
    __shared__ short Wl[D * 136];
    const int tid = threadIdx.x;
    const int row0 = blockIdx.x * GBM;

#pragma unroll
    for (int i = 0; i < 4; ++i) {
        int c = tid + i * 512;
        int r = c >> 4, ck = (c & 15) * 8;
        int grow = row0 + r;
        int4 v = make_int4(0, 0, 0, 0);
        if (grow < n) v = *(const int4*)&hin[(size_t)grow * D + ck];
        *(int4*)&Ah[r * 136 + ck] = v;
    }
#pragma unroll
    for (int i = 0; i < 4; ++i) {
        int c = tid + i * 512;
        int r = c >> 4, ck = (c & 15) * 8;
        *(int4*)&Wl[r * 136 + ck] = *(const int4*)&Wt[(size_t)r * D + ck];
    }
    __syncthreads();

    const int wid = tid >> 6;
    const int lane = tid & 63;
    const int lr = lane & 15;
    const int lg = lane >> 4;

    f32x4 acc[8];
#pragma unroll
    for (int fc = 0; fc < 8; ++fc) acc[fc] = (f32x4){0.f, 0.f, 0.f, 0.f};

#pragma unroll
    for (int ks = 0; ks < 4; ++ks) {
        int kb = ks * 32 + lg * 8;
        short8 y = *(const short8*)&Ah[(wid * 16 + lr) * 136 + kb];
#pragma unroll
        for (int fc = 0; fc < 8; ++fc) {
            short8 xf = *(const short8*)&Wl[(fc * 16 + lr) * 136 + kb];
            acc[fc] = __builtin_amdgcn_mfma_f32_16x16x32_bf16(xf, y, acc[fc], 0, 0, 0);
        }
    }

    int grow = row0 + wid * 16 + lr;
    if (grow < n) {
        float di = dinv[grow];
#pragma unroll
        for (int fc = 0; fc < 8; ++fc) {
            int gcol = fc * 16 + lg * 4;
            uint2 pk;
            pk.x = bf16r(acc[fc][0] * di) | (bf16r(acc[fc][1] * di) << 16);
            pk.y = bf16r(acc[fc][2] * di) | (bf16r(acc[fc][3] * di) << 16);
            *(uint2*)&mout[(size_t)grow * D + gcol] = pk;
        }
    }
}

// ---------------- fused aggregation + bias + BN + ReLU (bf16 in/out, f32 acc) ----------------
__global__ __launch_bounds__(256) void agg_bf16(const unsigned int* __restrict__ M,
                                                const int* __restrict__ rp,
                                                const int* __restrict__ aux,
                                                const int* __restrict__ csr,
                                                const float* __restrict__ dinv,
                                                const float* __restrict__ sc,
                                                const float* __restrict__ sh,
                                                unsigned int* __restrict__ H, int n, int Etot) {
    const int wid = threadIdx.x >> 6;
    const int lane = threadIdx.x & 63;
    const int row = blockIdx.x * 4 + wid;
    if (row >= n) return;

    unsigned int u = M[(unsigned)row * 64u + lane];
    float a0 = bf2f(u & 0xffffu);
    float a1 = bf2f(u >> 16);

    int e = rp[row] + aux[row >> 10];
    const int end = (row + 1 < n) ? rp[row + 1] + aux[(row + 1) >> 10] : Etot;
    const int n16 = (end - e) >> 4;

    if (n16 > 0) {
        int sa[16];
#pragma unroll
        for (int i = 0; i < 16; ++i) sa[i] = csr[e + i];
        for (int it = 0; it < n16; ++it) {
            int sb[16];
            if (it + 1 < n16) {
#pragma unroll
                for (int i = 0; i < 16; ++i) sb[i] = csr[e + 16 + i];
            } else {
#pragma unroll
                for (int i = 0; i < 16; ++i) sb[i] = 0;
            }
            unsigned int g[16];
#pragma unroll
            for (int i = 0; i < 16; ++i) g[i] = M[(unsigned)sa[i] * 64u + lane];
#pragma unroll
            for (int i = 0; i < 16; ++i) {
                a0 += bf2f(g[i] & 0xffffu);
                a1 += bf2f(g[i] >> 16);
            }
#pragma unroll
            for (int i = 0; i < 16; ++i) sa[i] = sb[i];
            e += 16;
        }
    }
    for (; e + 4 <= end; e += 4) {
        int s[4];
#pragma unroll
        for (int i = 0; i < 4; ++i) s[i] = csr[e + i];
        unsigned int g[4];
#pragma unroll
        for (int i = 0; i < 4; ++i) g[i] = M[(unsigned)s[i] * 64u + lane];
#pragma unroll
        for (int i = 0; i < 4; ++i) {
            a0 += bf2f(g[i] & 0xffffu);
            a1 += bf2f(g[i] >> 16);
        }
    }
    for (; e < end; ++e) {
        unsigned int gs = M[(unsigned)csr[e] * 64u + lane];
        a0 += bf2f(gs & 0xffffu);
        a1 += bf2f(gs >> 16);
    }

    float di = dinv[row];
    int c0 = lane * 2;
    float v0 = fmaxf(a0 * di * sc[c0] + sh[c0], 0.f);
    float v1 = fmaxf(a1 * di * sc[c0 + 1] + sh[c0 + 1], 0.f);
    H[(unsigned)row * 64u + lane] = bf16r(v0) | (bf16r(v1) << 16);
}

// ---------------- pooling ----------------
__global__ __launch_bounds__(64) void pool1(const unsigned int* __restrict__ H,
                                            const int* __restrict__ gstart,
                                            float4* __restrict__ pbuf) {
    int g = blockIdx.x, c = blockIdx.y;
    int lane = threadIdx.x;
    int beg = gstart[g], end = gstart[g + 1];
    int len = end - beg;
    int cb = beg + (int)(((long long)len * c) >> 3);
    int ce = beg + (int)(((long long)len * (c + 1)) >> 3);
    float s0 = 0.f, s1 = 0.f, m0 = -INFINITY, m1 = -INFINITY;
    int i = cb;
    for (; i + 2 <= ce; i += 2) {
        unsigned int ua = H[(size_t)i * 64 + lane];
        unsigned int ub = H[(size_t)(i + 1) * 64 + lane];
        float a0 = bf2f(ua & 0xffffu), a1 = bf2f(ua >> 16);
        float b0 = bf2f(ub & 0xffffu), b1 = bf2f(ub >> 16);
        s0 += a0 + b0; s1 += a1 + b1;
        m0 = fmaxf(m0, fmaxf(a0, b0)); m1 = fmaxf(m1, fmaxf(a1, b1));
    }
    for (; i < ce; ++i) {
        unsigned int ua = H[(size_t)i * 64 + lane];
        float a0 = bf2f(ua & 0xffffu), a1 = bf2f(ua >> 16);
        s0 += a0; s1 += a1;
        m0 = fmaxf(m0, a0); m1 = fmaxf(m1, a1);
    }
    pbuf[((size_t)g * 8 + c) * 64 + lane] = make_float4(s0, s1, m0, m1);
}

__global__ __launch_bounds__(64) void pool2(const float4* __restrict__ pbuf,
                                            const int* __restrict__ gstart,
                                            float* __restrict__ out) {
    int g = blockIdx.x;
    int lane = threadIdx.x;
    float s0 = 0.f, s1 = 0.f, m0 = -INFINITY, m1 = -INFINITY;
#pragma unroll
    for (int c = 0; c < 8; ++c) {
        float4 p = pbuf[((size_t)g * 8 + c) * 64 + lane];
        s0 += p.x; s1 += p.y;
        m0 = fmaxf(m0, p.z); m1 = fmaxf(m1, p.w);
    }
    float cnt = fmaxf((float)(gstart[g + 1] - gstart[g]), 1.0f);
    int c0 = lane * 2;
    out[g * (2 * D) + c0] = s0 / cnt;
    out[g * (2 * D) + c0 + 1] = s1 / cnt;
    out[g * (2 * D) + D + c0] = m0;
    out[g * (2 * D) + D + c0 + 1] = m1;
}

// ---------------- launch ----------------
extern "C" void kernel_launch(void* const* d_in, const int* in_sizes, int n_in,
                              void* d_out, int out_size, void* d_ws, size_t ws_size,
                              hipStream_t stream) {
    const float* x     = (const float*)d_in[0];
    const float* W     = (const float*)d_in[1];
    const float* b     = (const float*)d_in[2];
    const float* gamma = (const float*)d_in[3];
    const float* beta  = (const float*)d_in[4];
    const float* rmean = (const float*)d_in[5];
    const float* rvar  = (const float*)d_in[6];
    const int*   eidx  = (const int*)d_in[7];
    const int*   batch = (const int*)d_in[8];

    const int N = in_sizes[8];
    const int E = in_sizes[7] / 2;
    const int L = in_sizes[2] / D;
    const int G = out_size / (2 * D);

    const int* esrc = eidx;
    const int* edst = eidx + E;

    size_t off = 0;
    auto carve = [&](size_t bytes) { size_t cur = off; off += (bytes + 255) & ~(size_t)255; return cur; };
    char* base = (char*)d_ws;
    const int nb = (N + 1023) / 1024;

    int*            cnt  = (int*)           (base + carve((size_t)N * 4));
    int*            rp   = (int*)           (base + carve((size_t)(N + 1) * 4));
    int*            aux  = (int*)           (base + carve((size_t)nb * 4));
    float*          dinv = (float*)         (base + carve((size_t)N * 4));
    int*            rank = (int*)           (base + carve((size_t)E * 4));
    int*            csr  = (int*)           (base + carve((size_t)E * 4));
    unsigned short* hbuf = (unsigned short*)(base + carve((size_t)N * D * 2));
    unsigned short* mbuf = (unsigned short*)(base + carve((size_t)N * D * 2));
    unsigned short* Wt   = (unsigned short*)(base + carve((size_t)L * D * D * 2));
    float*          sc   = (float*)         (base + carve((size_t)L * D * 4));
    float*          shb  = (float*)         (base + carve((size_t)L * D * 4));
    int*            gst  = (int*)           (base + carve((size_t)(G + 1) * 4));
    float4*         pbuf = (float4*)        (base + carve((size_t)G * 8 * 64 * 16));
    (void)ws_size;

    hipMemsetAsync(cnt, 0, (size_t)N * 4, stream);

    const int cb = ((E + 3) / 4 + 255) / 256;          // count blocks
    const int gb = (N + GBM0 - 1) / GBM0;              // gemm0 blocks (64 rows, 256 thr)
    const int wb = (L * D * D + 255) / 256;            // wprep blocks
    const int bb = (N + 255) / 256;                    // bounds blocks
    const int gemmb = (N + GBM - 1) / GBM;
    const int fb = ((E + 3) / 4 + 255) / 256;          // fill blocks
    const int sb = (N * 16 + 255) / 256;               // scale blocks (uint4/thread)
    const int aggb = (N + 3) / 4;

    prep_fused<<<cb + gb + wb + bb, 256, 0, stream>>>(edst, cnt, rank, E,
                                                      x, mbuf, N,
                                                      W, b, gamma, beta, rmean, rvar,
                                                      Wt, sc, shb, L,
                                                      batch, gst, G, cb, gb, wb);
    scan1<<<nb, 256, 0, stream>>>(cnt, rp, aux, dinv, N);
    scan2<<<1, 256, 0, stream>>>(aux, nb);

    fill_scale<<<fb + sb, 256, 0, stream>>>(esrc, edst, rp, aux, rank, csr, E,
                                            (unsigned int*)mbuf, dinv, N, fb);

    agg_bf16<<<aggb, 256, 0, stream>>>((const unsigned int*)mbuf, rp, aux, csr, dinv,
                                       sc, shb, (unsigned int*)hbuf, N, E);

    for (int l = 1; l < L; ++l) {
        gemm_mfma<<<gemmb, 512, 0, stream>>>(hbuf, Wt + (size_t)l * D * D, dinv, mbuf, N);
        agg_bf16<<<aggb, 256, 0, stream>>>((const unsigned int*)mbuf, rp, aux, csr, dinv,
                                           sc + l * D, shb + l * D,
                                           (unsigned int*)hbuf, N, E);
    }

    pool1<<<dim3(G, 8), 64, 0, stream>>>((const unsigned int*)hbuf, gst, pbuf);
    pool2<<<G, 64, 0, stream>>>(pbuf, gst, (float*)d_out);
}

// Round 14
// 375.111 us; speedup vs baseline: 1.0012x; 1.0012x over previous
//
#include <hip/hip_runtime.h>
#include <math.h>
#include <float.h>

#define D 128

typedef short short8 __attribute__((ext_vector_type(8)));
typedef float f32x4 __attribute__((ext_vector_type(4)));

__device__ __forceinline__ unsigned int bf16r(float f) {
    unsigned int u = __float_as_uint(f);
    return (u + 0x7fffu + ((u >> 16) & 1u)) >> 16;   // RNE
}
__device__ __forceinline__ float bf2f(unsigned int lo16) {
    return __uint_as_float(lo16 << 16);
}

// ---------------- fused prep: count_rank | gemm0_raw | wprep | bounds ----------------
// 512-thr blocks: 4 blocks/CU x 8 waves = 32 waves/CU even with 34KB LDS, so the
// gemm0 role's LDS no longer throttles the count role's occupancy (R13 lesson).
#define GBM0 128
__global__ __launch_bounds__(512) void prep_fused(
    const int* __restrict__ dst, int* __restrict__ cnt, int* __restrict__ rank, int E,
    const float* __restrict__ x, unsigned short* __restrict__ mraw, int n,
    const float* __restrict__ W, const float* __restrict__ b,
    const float* __restrict__ gamma, const float* __restrict__ beta,
    const float* __restrict__ rmean, const float* __restrict__ rvar,
    unsigned short* __restrict__ Wt, float* __restrict__ sc, float* __restrict__ sh, int L_,
    const int* __restrict__ batch, int* __restrict__ gstart, int G,
    int cb, int gb, int wb) {
    __shared__ short Wl[D * 136];
    const int blk = blockIdx.x;
    const int tid = threadIdx.x;
    if (blk < cb) {
        // ---- count + rank (batch-4) ----
        int base = (blk * 512 + tid) * 4;
        if (base + 4 <= E) {
            int4 d = *(const int4*)&dst[base];
            int r0 = atomicAdd(&cnt[d.x], 1);
            int r1 = atomicAdd(&cnt[d.y], 1);
            int r2 = atomicAdd(&cnt[d.z], 1);
            int r3 = atomicAdd(&cnt[d.w], 1);
            *(int4*)&rank[base] = make_int4(r0, r1, r2, r3);
        } else if (base < E) {
            for (int e = base; e < E; ++e) rank[e] = atomicAdd(&cnt[dst[e]], 1);
        }
    } else if (blk < cb + gb) {
        // ---- layer-0 GEMM, un-scaled: mraw[r][:] = x[r][:] @ W0 ----
        // stage W0^T into LDS: coalesced f32 read, transposed bf16 write
#pragma unroll
        for (int i = 0; i < 32; ++i) {
            int t = i * 512 + tid;               // 0..16383
            int k = t >> 7, r = t & 127;         // W0[k][r]
            Wl[r * 136 + k] = (short)bf16r(W[t]);
        }
        __syncthreads();

        const int row0 = (blk - cb) * GBM0;
        const int wid = tid >> 6;                // 8 waves -> 16 rows each
        const int lane = tid & 63;
        const int lr = lane & 15;
        const int lg = lane >> 4;
        const int grow = row0 + wid * 16 + lr;
        const bool valid = grow < n;

        f32x4 acc[8];
#pragma unroll
        for (int fc = 0; fc < 8; ++fc) acc[fc] = (f32x4){0.f, 0.f, 0.f, 0.f};

#pragma unroll
        for (int ks = 0; ks < 4; ++ks) {
            int kb = ks * 32 + lg * 8;
            float4 va = make_float4(0.f, 0.f, 0.f, 0.f);
            float4 vb = make_float4(0.f, 0.f, 0.f, 0.f);
            if (valid) {
                va = *(const float4*)&x[(size_t)grow * D + kb];
                vb = *(const float4*)&x[(size_t)grow * D + kb + 4];
            }
            uint4 pk;
            pk.x = bf16r(va.x) | (bf16r(va.y) << 16);
            pk.y = bf16r(va.z) | (bf16r(va.w) << 16);
            pk.z = bf16r(vb.x) | (bf16r(vb.y) << 16);
            pk.w = bf16r(vb.z) | (bf16r(vb.w) << 16);
            short8 y = *(short8*)&pk;
#pragma unroll
            for (int fc = 0; fc < 8; ++fc) {
                short8 xf = *(const short8*)&Wl[(fc * 16 + lr) * 136 + kb];
                acc[fc] = __builtin_amdgcn_mfma_f32_16x16x32_bf16(xf, y, acc[fc], 0, 0, 0);
            }
        }

        if (valid) {
#pragma unroll
            for (int fc = 0; fc < 8; ++fc) {
                int gcol = fc * 16 + lg * 4;
                uint2 pk;
                pk.x = bf16r(acc[fc][0]) | (bf16r(acc[fc][1]) << 16);
                pk.y = bf16r(acc[fc][2]) | (bf16r(acc[fc][3]) << 16);
                *(uint2*)&mraw[(size_t)grow * D + gcol] = pk;
            }
        }
    } else if (blk < cb + gb + wb) {
        // ---- wprep: W transpose -> bf16, BN fold ----
        int t = (blk - cb - gb) * 512 + tid;
        int total = L_ * D * D;
        if (t < total) {
            int l = t / (D * D), rem = t % (D * D);
            int r = rem >> 7, k = rem & 127;      // Wt[l][r][k] = W[l][k][r]
            Wt[t] = (unsigned short)bf16r(W[l * D * D + k * D + r]);
        }
        if (t < L_ * D) {
            float inv = rsqrtf(rvar[t] + 1e-5f);
            float s = inv * gamma[t];
            sc[t] = s;
            sh[t] = (b[t] - rmean[t]) * s + beta[t];
        }
    } else {
        // ---- bounds: graph start offsets from sorted batch ----
        int i = (blk - cb - gb - wb) * 512 + tid;
        if (i >= n) return;
        int g = batch[i];
        int gp = (i == 0) ? -1 : batch[i - 1];
        for (int gg = gp + 1; gg <= g; ++gg) gstart[gg] = i;
        if (i == n - 1) for (int gg = g + 1; gg <= G; ++gg) gstart[gg] = n;
    }
}

// ---------------- scans (block-local exclusive; consumers add aux[idx>>10]) ----------------

__global__ void scan1(const int* __restrict__ cnt, int* __restrict__ rp, int* __restrict__ aux,
                      float* __restrict__ dinv, int n) {
    __shared__ int sh[256];
    int tid = threadIdx.x;
    int base = blockIdx.x * 1024 + tid * 4;
    int v[4]; int s = 0;
#pragma unroll
    for (int i = 0; i < 4; i++) {
        int idx = base + i;
        int t = (idx < n) ? cnt[idx] : 0;
        if (idx < n) dinv[idx] = rsqrtf((float)t + 1.0f);   // +1 self-loop
        v[i] = s; s += t;
    }
    sh[tid] = s; __syncthreads();
    for (int off = 1; off < 256; off <<= 1) {
        int t = (tid >= off) ? sh[tid - off] : 0;
        __syncthreads();
        sh[tid] += t;
        __syncthreads();
    }
    int excl = sh[tid] - s;
#pragma unroll
    for (int i = 0; i < 4; i++) { int idx = base + i; if (idx < n) rp[idx] = excl + v[i]; }
    if (tid == 255) aux[blockIdx.x] = sh[255];
}

__global__ void scan2(int* aux, int nb) {
    __shared__ int sh[256];
    int tid = threadIdx.x;
    int v = (tid < nb) ? aux[tid] : 0;
    sh[tid] = v; __syncthreads();
    for (int off = 1; off < 256; off <<= 1) {
        int t = (tid >= off) ? sh[tid - off] : 0;
        __syncthreads();
        sh[tid] += t;
        __syncthreads();
    }
    if (tid < nb) aux[tid] = sh[tid] - v;   // exclusive
}

// ---------------- fused: fill | scale m_raw by dinv ----------------
// fill is latency-bound: the streaming dinv-scale of layer-0 m rides free.
__global__ __launch_bounds__(256) void fill_scale(
    const int* __restrict__ src, const int* __restrict__ dst,
    const int* __restrict__ rp, const int* __restrict__ aux,
    const int* __restrict__ rank, int* __restrict__ csr, int E,
    unsigned int* __restrict__ M, const float* __restrict__ dinv, int n,
    int fb) {
    const int blk = blockIdx.x;
    const int tid = threadIdx.x;
    if (blk < fb) {
        // ---- fill: atomic-free scatter, batch-4 ----
        int base = (blk * 256 + tid) * 4;
        if (base + 4 <= E) {
            int4 d = *(const int4*)&dst[base];
            int4 s = *(const int4*)&src[base];
            int4 r = *(const int4*)&rank[base];
            int p0 = rp[d.x] + aux[d.x >> 10];
            int p1 = rp[d.y] + aux[d.y >> 10];
            int p2 = rp[d.z] + aux[d.z >> 10];
            int p3 = rp[d.w] + aux[d.w >> 10];
            csr[p0 + r.x] = s.x;
            csr[p1 + r.y] = s.y;
            csr[p2 + r.z] = s.z;
            csr[p3 + r.w] = s.w;
        } else if (base < E) {
            for (int e = base; e < E; ++e)
                csr[rp[dst[e]] + aux[dst[e] >> 10] + rank[e]] = src[e];
        }
    } else {
        // ---- scale: M[row][:] *= dinv[row] (in-place bf16 RMW, uint4/thread) ----
        int t = (blk - fb) * 256 + tid;          // uint4 index
        int total4 = n * 16;                      // 64 uints/row = 16 uint4
        if (t >= total4) return;
        int row = t >> 4;
        float di = dinv[row];
        uint4 v = *(uint4*)&M[(size_t)t * 4];
        uint4 o;
        o.x = bf16r(bf2f(v.x & 0xffffu) * di) | (bf16r(bf2f(v.x >> 16) * di) << 16);
        o.y = bf16r(bf2f(v.y & 0xffffu) * di) | (bf16r(bf2f(v.y >> 16) * di) << 16);
        o.z = bf16r(bf2f(v.z & 0xffffu) * di) | (bf16r(bf2f(v.z >> 16) * di) << 16);
        o.w = bf16r(bf2f(v.w & 0xffffu) * di) | (bf16r(bf2f(v.w >> 16) * di) << 16);
        *(uint4*)&M[(size_t)t * 4] = o;
    }
}

// ---------------- standalone staged GEMM (layers 1,2) ----------------
#define GBM 128
__global__ __launch_bounds__(512) void gemm_mfma(const unsigned short* __restrict__ hin,
                                                 const unsigned short* __restrict__ Wt,
                                                 const float* __restrict__ dinv,
                                                 unsigned short* __restrict__ mout, int n) {
    __shared__ short Ah[GBM * 136];
    __shared__ short Wl[D * 136];
    const int tid = threadIdx.x;
    const int row0 = blockIdx.x * GBM;

#pragma unroll
    for (int i = 0; i < 4; ++i) {
        int c = tid + i * 512;
        int r = c >> 4, ck = (c & 15) * 8;
        int grow = row0 + r;
        int4 v = make_int4(0, 0, 0, 0);
        if (grow < n) v = *(const int4*)&hin[(size_t)grow * D + ck];
        *(int4*)&Ah[r * 136 + ck] = v;
    }
#pragma unroll
    for (int i = 0; i < 4; ++i) {
        int c = tid + i * 512;
        int r = c >> 4, ck = (c & 15) * 8;
        *(int4*)&Wl[r * 136 + ck] = *(const int4*)&Wt[(size_t)r * D + ck];
    }
    __syncthreads();

    const int wid = tid >> 6;
    const int lane = tid & 63;
    const int lr = lane & 15;
    const int lg = lane >> 4;

    f32x4 acc[8];
#pragma unroll
    for (int fc = 0; fc < 8; ++fc) acc[fc] = (f32x4){0.f, 0.f, 0.f, 0.f};

#pragma unroll
    for (int ks = 0; ks < 4; ++ks) {
        int kb = ks * 32 + lg * 8;
        short8 y = *(const short8*)&Ah[(wid * 16 + lr) * 136 + kb];
#pragma unroll
        for (int fc = 0; fc < 8; ++fc) {
            short8 xf = *(const short8*)&Wl[(fc * 16 + lr) * 136 + kb];
            acc[fc] = __builtin_amdgcn_mfma_f32_16x16x32_bf16(xf, y, acc[fc], 0, 0, 0);
        }
    }

    int grow = row0 + wid * 16 + lr;
    if (grow < n) {
        float di = dinv[grow];
#pragma unroll
        for (int fc = 0; fc < 8; ++fc) {
            int gcol = fc * 16 + lg * 4;
            uint2 pk;
            pk.x = bf16r(acc[fc][0] * di) | (bf16r(acc[fc][1] * di) << 16);
            pk.y = bf16r(acc[fc][2] * di) | (bf16r(acc[fc][3] * di) << 16);
            *(uint2*)&mout[(size_t)grow * D + gcol] = pk;
        }
    }
}

// ---------------- fused aggregation + bias + BN + ReLU (bf16 in/out, f32 acc) ----------------
__global__ __launch_bounds__(256) void agg_bf16(const unsigned int* __restrict__ M,
                                                const int* __restrict__ rp,
                                                const int* __restrict__ aux,
                                                const int* __restrict__ csr,
                                                const float* __restrict__ dinv,
                                                const float* __restrict__ sc,
                                                const float* __restrict__ sh,
                                                unsigned int* __restrict__ H, int n, int Etot) {
    const int wid = threadIdx.x >> 6;
    const int lane = threadIdx.x & 63;
    const int row = blockIdx.x * 4 + wid;
    if (row >= n) return;

    unsigned int u = M[(unsigned)row * 64u + lane];
    float a0 = bf2f(u & 0xffffu);
    float a1 = bf2f(u >> 16);

    int e = rp[row] + aux[row >> 10];
    const int end = (row + 1 < n) ? rp[row + 1] + aux[(row + 1) >> 10] : Etot;
    const int n16 = (end - e) >> 4;

    if (n16 > 0) {
        int sa[16];
#pragma unroll
        for (int i = 0; i < 16; ++i) sa[i] = csr[e + i];
        for (int it = 0; it < n16; ++it) {
            int sb[16];
            if (it + 1 < n16) {
#pragma unroll
                for (int i = 0; i < 16; ++i) sb[i] = csr[e + 16 + i];
            } else {
#pragma unroll
                for (int i = 0; i < 16; ++i) sb[i] = 0;
            }
            unsigned int g[16];
#pragma unroll
            for (int i = 0; i < 16; ++i) g[i] = M[(unsigned)sa[i] * 64u + lane];
#pragma unroll
            for (int i = 0; i < 16; ++i) {
                a0 += bf2f(g[i] & 0xffffu);
                a1 += bf2f(g[i] >> 16);
            }
#pragma unroll
            for (int i = 0; i < 16; ++i) sa[i] = sb[i];
            e += 16;
        }
    }
    for (; e + 4 <= end; e += 4) {
        int s[4];
#pragma unroll
        for (int i = 0; i < 4; ++i) s[i] = csr[e + i];
        unsigned int g[4];
#pragma unroll
        for (int i = 0; i < 4; ++i) g[i] = M[(unsigned)s[i] * 64u + lane];
#pragma unroll
        for (int i = 0; i < 4; ++i) {
            a0 += bf2f(g[i] & 0xffffu);
            a1 += bf2f(g[i] >> 16);
        }
    }
    for (; e < end; ++e) {
        unsigned int gs = M[(unsigned)csr[e] * 64u + lane];
        a0 += bf2f(gs & 0xffffu);
        a1 += bf2f(gs >> 16);
    }

    float di = dinv[row];
    int c0 = lane * 2;
    float v0 = fmaxf(a0 * di * sc[c0] + sh[c0], 0.f);
    float v1 = fmaxf(a1 * di * sc[c0 + 1] + sh[c0 + 1], 0.f);
    H[(unsigned)row * 64u + lane] = bf16r(v0) | (bf16r(v1) << 16);
}

// ---------------- pooling ----------------
__global__ __launch_bounds__(64) void pool1(const unsigned int* __restrict__ H,
                                            const int* __restrict__ gstart,
                                            float4* __restrict__ pbuf) {
    int g = blockIdx.x, c = blockIdx.y;
    int lane = threadIdx.x;
    int beg = gstart[g], end = gstart[g + 1];
    int len = end - beg;
    int cb = beg + (int)(((long long)len * c) >> 3);
    int ce = beg + (int)(((long long)len * (c + 1)) >> 3);
    float s0 = 0.f, s1 = 0.f, m0 = -INFINITY, m1 = -INFINITY;
    int i = cb;
    for (; i + 2 <= ce; i += 2) {
        unsigned int ua = H[(size_t)i * 64 + lane];
        unsigned int ub = H[(size_t)(i + 1) * 64 + lane];
        float a0 = bf2f(ua & 0xffffu), a1 = bf2f(ua >> 16);
        float b0 = bf2f(ub & 0xffffu), b1 = bf2f(ub >> 16);
        s0 += a0 + b0; s1 += a1 + b1;
        m0 = fmaxf(m0, fmaxf(a0, b0)); m1 = fmaxf(m1, fmaxf(a1, b1));
    }
    for (; i < ce; ++i) {
        unsigned int ua = H[(size_t)i * 64 + lane];
        float a0 = bf2f(ua & 0xffffu), a1 = bf2f(ua >> 16);
        s0 += a0; s1 += a1;
        m0 = fmaxf(m0, a0); m1 = fmaxf(m1, a1);
    }
    pbuf[((size_t)g * 8 + c) * 64 + lane] = make_float4(s0, s1, m0, m1);
}

__global__ __launch_bounds__(64) void pool2(const float4* __restrict__ pbuf,
                                            const int* __restrict__ gstart,
                                            float* __restrict__ out) {
    int g = blockIdx.x;
    int lane = threadIdx.x;
    float s0 = 0.f, s1 = 0.f, m0 = -INFINITY, m1 = -INFINITY;
#pragma unroll
    for (int c = 0; c < 8; ++c) {
        float4 p = pbuf[((size_t)g * 8 + c) * 64 + lane];
        s0 += p.x; s1 += p.y;
        m0 = fmaxf(m0, p.z); m1 = fmaxf(m1, p.w);
    }
    float cnt = fmaxf((float)(gstart[g + 1] - gstart[g]), 1.0f);
    int c0 = lane * 2;
    out[g * (2 * D) + c0] = s0 / cnt;
    out[g * (2 * D) + c0 + 1] = s1 / cnt;
    out[g * (2 * D) + D + c0] = m0;
    out[g * (2 * D) + D + c0 + 1] = m1;
}

// ---------------- launch ----------------
extern "C" void kernel_launch(void* const* d_in, const int* in_sizes, int n_in,
                              void* d_out, int out_size, void* d_ws, size_t ws_size,
                              hipStream_t stream) {
    const float* x     = (const float*)d_in[0];
    const float* W     = (const float*)d_in[1];
    const float* b     = (const float*)d_in[2];
    const float* gamma = (const float*)d_in[3];
    const float* beta  = (const float*)d_in[4];
    const float* rmean = (const float*)d_in[5];
    const float* rvar  = (const float*)d_in[6];
    const int*   eidx  = (const int*)d_in[7];
    const int*   batch = (const int*)d_in[8];

    const int N = in_sizes[8];
    const int E = in_sizes[7] / 2;
    const int L = in_sizes[2] / D;
    const int G = out_size / (2 * D);

    const int* esrc = eidx;
    const int* edst = eidx + E;

    size_t off = 0;
    auto carve = [&](size_t bytes) { size_t cur = off; off += (bytes + 255) & ~(size_t)255; return cur; };
    char* base = (char*)d_ws;
    const int nb = (N + 1023) / 1024;

    int*            cnt  = (int*)           (base + carve((size_t)N * 4));
    int*            rp   = (int*)           (base + carve((size_t)(N + 1) * 4));
    int*            aux  = (int*)           (base + carve((size_t)nb * 4));
    float*          dinv = (float*)         (base + carve((size_t)N * 4));
    int*            rank = (int*)           (base + carve((size_t)E * 4));
    int*            csr  = (int*)           (base + carve((size_t)E * 4));
    unsigned short* hbuf = (unsigned short*)(base + carve((size_t)N * D * 2));
    unsigned short* mbuf = (unsigned short*)(base + carve((size_t)N * D * 2));
    unsigned short* Wt   = (unsigned short*)(base + carve((size_t)L * D * D * 2));
    float*          sc   = (float*)         (base + carve((size_t)L * D * 4));
    float*          shb  = (float*)         (base + carve((size_t)L * D * 4));
    int*            gst  = (int*)           (base + carve((size_t)(G + 1) * 4));
    float4*         pbuf = (float4*)        (base + carve((size_t)G * 8 * 64 * 16));
    (void)ws_size;

    hipMemsetAsync(cnt, 0, (size_t)N * 4, stream);

    const int cb = ((E + 3) / 4 + 511) / 512;          // count blocks (512 thr)
    const int gb = (N + GBM0 - 1) / GBM0;              // gemm0 blocks (128 rows, 512 thr)
    const int wb = (L * D * D + 511) / 512;            // wprep blocks
    const int bb = (N + 511) / 512;                    // bounds blocks
    const int gemmb = (N + GBM - 1) / GBM;
    const int fb = ((E + 3) / 4 + 255) / 256;          // fill blocks
    const int sb = (N * 16 + 255) / 256;               // scale blocks (uint4/thread)
    const int aggb = (N + 3) / 4;

    prep_fused<<<cb + gb + wb + bb, 512, 0, stream>>>(edst, cnt, rank, E,
                                                      x, mbuf, N,
                                                      W, b, gamma, beta, rmean, rvar,
                                                      Wt, sc, shb, L,
                                                      batch, gst, G, cb, gb, wb);
    scan1<<<nb, 256, 0, stream>>>(cnt, rp, aux, dinv, N);
    scan2<<<1, 256, 0, stream>>>(aux, nb);

    fill_scale<<<fb + sb, 256, 0, stream>>>(esrc, edst, rp, aux, rank, csr, E,
                                            (unsigned int*)mbuf, dinv, N, fb);

    agg_bf16<<<aggb, 256, 0, stream>>>((const unsigned int*)mbuf, rp, aux, csr, dinv,
                                       sc, shb, (unsigned int*)hbuf, N, E);

    for (int l = 1; l < L; ++l) {
        gemm_mfma<<<gemmb, 512, 0, stream>>>(hbuf, Wt + (size_t)l * D * D, dinv, mbuf, N);
        agg_bf16<<<aggb, 256, 0, stream>>>((const unsigned int*)mbuf, rp, aux, csr, dinv,
                                           sc + l * D, shb + l * D,
                                           (unsigned int*)hbuf, N, E);
    }

    pool1<<<dim3(G, 8), 64, 0, stream>>>((const unsigned int*)hbuf, gst, pbuf);
    pool2<<<G, 64, 0, stream>>>(pbuf, gst, (float*)d_out);
}

// Round 15
// 367.069 us; speedup vs baseline: 1.0232x; 1.0219x over previous
//
#include <hip/hip_runtime.h>
#include <math.h>
#include <float.h>

#define D 128

typedef short short8 __attribute__((ext_vector_type(8)));
typedef float f32x4 __attribute__((ext_vector_type(4)));

__device__ __forceinline__ unsigned int bf16r(float f) {
    unsigned int u = __float_as_uint(f);
    return (u + 0x7fffu + ((u >> 16) & 1u)) >> 16;   // RNE
}
__device__ __forceinline__ float bf2f(unsigned int lo16) {
    return __uint_as_float(lo16 << 16);
}

// ---------------- fused prep: count_rank | wprep | bounds ----------------
// R11-proven: only LOW-TRAFFIC work rides free under the atomic wall
// (R13/R14 falsified heavy-traffic riders: atomics + memory traffic share
// fabric transaction capacity).
__global__ __launch_bounds__(256) void prep_fused(
    const int* __restrict__ dst, int* __restrict__ cnt, int* __restrict__ rank, int E,
    const float* __restrict__ W, const float* __restrict__ b,
    const float* __restrict__ gamma, const float* __restrict__ beta,
    const float* __restrict__ rmean, const float* __restrict__ rvar,
    unsigned short* __restrict__ Wt, float* __restrict__ sc, float* __restrict__ sh, int L_,
    const int* __restrict__ batch, int* __restrict__ gstart, int n, int G,
    int cb, int wb) {
    int blk = blockIdx.x;
    int tid = threadIdx.x;
    if (blk < cb) {
        // ---- count + rank (batch-4) ----
        int base = (blk * 256 + tid) * 4;
        if (base + 4 <= E) {
            int4 d = *(const int4*)&dst[base];
            int r0 = atomicAdd(&cnt[d.x], 1);
            int r1 = atomicAdd(&cnt[d.y], 1);
            int r2 = atomicAdd(&cnt[d.z], 1);
            int r3 = atomicAdd(&cnt[d.w], 1);
            *(int4*)&rank[base] = make_int4(r0, r1, r2, r3);
        } else if (base < E) {
            for (int e = base; e < E; ++e) rank[e] = atomicAdd(&cnt[dst[e]], 1);
        }
    } else if (blk < cb + wb) {
        // ---- wprep: W transpose -> bf16, BN fold ----
        int t = (blk - cb) * 256 + tid;
        int total = L_ * D * D;
        if (t < total) {
            int l = t / (D * D), rem = t % (D * D);
            int r = rem >> 7, k = rem & 127;          // Wt[l][r][k] = W[l][k][r]
            Wt[t] = (unsigned short)bf16r(W[l * D * D + k * D + r]);
        }
        if (t < L_ * D) {
            float inv = rsqrtf(rvar[t] + 1e-5f);
            float s = inv * gamma[t];
            sc[t] = s;
            sh[t] = (b[t] - rmean[t]) * s + beta[t];
        }
    } else {
        // ---- bounds: graph start offsets from sorted batch ----
        int i = (blk - cb - wb) * 256 + tid;
        if (i >= n) return;
        int g = batch[i];
        int gp = (i == 0) ? -1 : batch[i - 1];
        for (int gg = gp + 1; gg <= g; ++gg) gstart[gg] = i;
        if (i == n - 1) for (int gg = g + 1; gg <= G; ++gg) gstart[gg] = n;
    }
}

// ---------------- scans (block-local exclusive; consumers add aux[idx>>10]) ----------------

__global__ void scan1(const int* __restrict__ cnt, int* __restrict__ rp, int* __restrict__ aux,
                      float* __restrict__ dinv, int n) {
    __shared__ int sh[256];
    int tid = threadIdx.x;
    int base = blockIdx.x * 1024 + tid * 4;
    int v[4]; int s = 0;
#pragma unroll
    for (int i = 0; i < 4; i++) {
        int idx = base + i;
        int t = (idx < n) ? cnt[idx] : 0;
        if (idx < n) dinv[idx] = rsqrtf((float)t + 1.0f);   // +1 self-loop
        v[i] = s; s += t;
    }
    sh[tid] = s; __syncthreads();
    for (int off = 1; off < 256; off <<= 1) {
        int t = (tid >= off) ? sh[tid - off] : 0;
        __syncthreads();
        sh[tid] += t;
        __syncthreads();
    }
    int excl = sh[tid] - s;
#pragma unroll
    for (int i = 0; i < 4; i++) { int idx = base + i; if (idx < n) rp[idx] = excl + v[i]; }
    if (tid == 255) aux[blockIdx.x] = sh[255];
}

__global__ void scan2(int* aux, int nb) {
    __shared__ int sh[256];
    int tid = threadIdx.x;
    int v = (tid < nb) ? aux[tid] : 0;
    sh[tid] = v; __syncthreads();
    for (int off = 1; off < 256; off <<= 1) {
        int t = (tid >= off) ? sh[tid - off] : 0;
        __syncthreads();
        sh[tid] += t;
        __syncthreads();
    }
    if (tid < nb) aux[tid] = sh[tid] - v;   // exclusive
}

// ---------------- gemm0 body (no A-tile LDS: each wave reads its own rows) ----------------
#define GBM 128
__device__ __forceinline__ void gemm0_body(short* Wl, const float* __restrict__ x,
                                           const unsigned short* __restrict__ Wt,
                                           const float* __restrict__ dinv,
                                           unsigned short* __restrict__ mout, int n, int blk) {
    const int tid = threadIdx.x;
    const int row0 = blk * GBM;

    // stage Wt (128x128 bf16): 2048 chunks of 8 bf16
#pragma unroll
    for (int i = 0; i < 4; ++i) {
        int c = tid + i * 512;
        int r = c >> 4, ck = (c & 15) * 8;
        *(int4*)&Wl[r * 136 + ck] = *(const int4*)&Wt[(size_t)r * D + ck];
    }
    __syncthreads();

    const int wid = tid >> 6;          // wave 0..7 -> nodes [wid*16, wid*16+16)
    const int lane = tid & 63;
    const int lr = lane & 15;
    const int lg = lane >> 4;

    const int grow = row0 + wid * 16 + lr;
    const bool valid = grow < n;

    f32x4 acc[8];
#pragma unroll
    for (int fc = 0; fc < 8; ++fc) acc[fc] = (f32x4){0.f, 0.f, 0.f, 0.f};

#pragma unroll
    for (int ks = 0; ks < 4; ++ks) {
        int kb = ks * 32 + lg * 8;
        float4 va = make_float4(0.f, 0.f, 0.f, 0.f);
        float4 vb = make_float4(0.f, 0.f, 0.f, 0.f);
        if (valid) {
            va = *(const float4*)&x[(size_t)grow * D + kb];
            vb = *(const float4*)&x[(size_t)grow * D + kb + 4];
        }
        uint4 pk;
        pk.x = bf16r(va.x) | (bf16r(va.y) << 16);
        pk.y = bf16r(va.z) | (bf16r(va.w) << 16);
        pk.z = bf16r(vb.x) | (bf16r(vb.y) << 16);
        pk.w = bf16r(vb.z) | (bf16r(vb.w) << 16);
        short8 y = *(short8*)&pk;
#pragma unroll
        for (int fc = 0; fc < 8; ++fc) {
            short8 xf = *(const short8*)&Wl[(fc * 16 + lr) * 136 + kb];
            acc[fc] = __builtin_amdgcn_mfma_f32_16x16x32_bf16(xf, y, acc[fc], 0, 0, 0);
        }
    }

    if (valid) {
        float di = dinv[grow];
#pragma unroll
        for (int fc = 0; fc < 8; ++fc) {
            int gcol = fc * 16 + lg * 4;
            uint2 pk;
            pk.x = bf16r(acc[fc][0] * di) | (bf16r(acc[fc][1] * di) << 16);
            pk.y = bf16r(acc[fc][2] * di) | (bf16r(acc[fc][3] * di) << 16);
            *(uint2*)&mout[(size_t)grow * D + gcol] = pk;
        }
    }
}

// ---------------- fused: fill | gemm0 ----------------
// fill is latency-bound (VALUBusy 0.6%) -> gemm0's MFMA work hides under it (R11-proven).
__global__ __launch_bounds__(512) void fused_fill_gemm0(
    const float* __restrict__ x, const unsigned short* __restrict__ Wt,
    const float* __restrict__ dinv, unsigned short* __restrict__ mout, int n,
    const int* __restrict__ src, const int* __restrict__ dst,
    const int* __restrict__ rp, const int* __restrict__ aux,
    const int* __restrict__ rank, int* __restrict__ csr, int E, int gemmb) {
    __shared__ short Wl[D * 136];
    if ((int)blockIdx.x < gemmb) {
        gemm0_body(Wl, x, Wt, dinv, mout, n, blockIdx.x);
    } else {
        int gblk = blockIdx.x - gemmb;
        int base = (gblk * 512 + (int)threadIdx.x) * 4;
        if (base + 4 <= E) {
            int4 d = *(const int4*)&dst[base];
            int4 s = *(const int4*)&src[base];
            int4 r = *(const int4*)&rank[base];
            int p0 = rp[d.x] + aux[d.x >> 10];
            int p1 = rp[d.y] + aux[d.y >> 10];
            int p2 = rp[d.z] + aux[d.z >> 10];
            int p3 = rp[d.w] + aux[d.w >> 10];
            csr[p0 + r.x] = s.x;
            csr[p1 + r.y] = s.y;
            csr[p2 + r.z] = s.z;
            csr[p3 + r.w] = s.w;
        } else if (base < E) {
            for (int e = base; e < E; ++e)
                csr[rp[dst[e]] + aux[dst[e] >> 10] + rank[e]] = src[e];
        }
    }
}

// ---------------- standalone staged GEMM (layers 1,2) ----------------
__global__ __launch_bounds__(512) void gemm_mfma(const unsigned short* __restrict__ hin,
                                                 const unsigned short* __restrict__ Wt,
                                                 const float* __restrict__ dinv,
                                                 unsigned short* __restrict__ mout, int n) {
    __shared__ short Ah[GBM * 136];
    __shared__ short Wl[D * 136];
    const int tid = threadIdx.x;
    const int row0 = blockIdx.x * GBM;

#pragma unroll
    for (int i = 0; i < 4; ++i) {
        int c = tid + i * 512;
        int r = c >> 4, ck = (c & 15) * 8;
        int grow = row0 + r;
        int4 v = make_int4(0, 0, 0, 0);
        if (grow < n) v = *(const int4*)&hin[(size_t)grow * D + ck];
        *(int4*)&Ah[r * 136 + ck] = v;
    }
#pragma unroll
    for (int i = 0; i < 4; ++i) {
        int c = tid + i * 512;
        int r = c >> 4, ck = (c & 15) * 8;
        *(int4*)&Wl[r * 136 + ck] = *(const int4*)&Wt[(size_t)r * D + ck];
    }
    __syncthreads();

    const int wid = tid >> 6;
    const int lane = tid & 63;
    const int lr = lane & 15;
    const int lg = lane >> 4;

    f32x4 acc[8];
#pragma unroll
    for (int fc = 0; fc < 8; ++fc) acc[fc] = (f32x4){0.f, 0.f, 0.f, 0.f};

#pragma unroll
    for (int ks = 0; ks < 4; ++ks) {
        int kb = ks * 32 + lg * 8;
        short8 y = *(const short8*)&Ah[(wid * 16 + lr) * 136 + kb];
#pragma unroll
        for (int fc = 0; fc < 8; ++fc) {
            short8 xf = *(const short8*)&Wl[(fc * 16 + lr) * 136 + kb];
            acc[fc] = __builtin_amdgcn_mfma_f32_16x16x32_bf16(xf, y, acc[fc], 0, 0, 0);
        }
    }

    int grow = row0 + wid * 16 + lr;
    if (grow < n) {
        float di = dinv[grow];
#pragma unroll
        for (int fc = 0; fc < 8; ++fc) {
            int gcol = fc * 16 + lg * 4;
            uint2 pk;
            pk.x = bf16r(acc[fc][0] * di) | (bf16r(acc[fc][1] * di) << 16);
            pk.y = bf16r(acc[fc][2] * di) | (bf16r(acc[fc][3] * di) << 16);
            *(uint2*)&mout[(size_t)grow * D + gcol] = pk;
        }
    }
}

// ---------------- fused aggregation + bias + BN + ReLU (bf16 in/out, f32 acc) ----------------
__global__ __launch_bounds__(256) void agg_bf16(const unsigned int* __restrict__ M,
                                                const int* __restrict__ rp,
                                                const int* __restrict__ aux,
                                                const int* __restrict__ csr,
                                                const float* __restrict__ dinv,
                                                const float* __restrict__ sc,
                                                const float* __restrict__ sh,
                                                unsigned int* __restrict__ H, int n, int Etot) {
    const int wid = threadIdx.x >> 6;
    const int lane = threadIdx.x & 63;
    const int row = blockIdx.x * 4 + wid;
    if (row >= n) return;

    unsigned int u = M[(unsigned)row * 64u + lane];
    float a0 = bf2f(u & 0xffffu);
    float a1 = bf2f(u >> 16);

    int e = rp[row] + aux[row >> 10];
    const int end = (row + 1 < n) ? rp[row + 1] + aux[(row + 1) >> 10] : Etot;
    const int n16 = (end - e) >> 4;

    if (n16 > 0) {
        int sa[16];
#pragma unroll
        for (int i = 0; i < 16; ++i) sa[i] = csr[e + i];
        for (int it = 0; it < n16; ++it) {
            int sb[16];
            if (it + 1 < n16) {
#pragma unroll
                for (int i = 0; i < 16; ++i) sb[i] = csr[e + 16 + i];
            } else {
#pragma unroll
                for (int i = 0; i < 16; ++i) sb[i] = 0;
            }
            unsigned int g[16];
#pragma unroll
            for (int i = 0; i < 16; ++i) g[i] = M[(unsigned)sa[i] * 64u + lane];
#pragma unroll
            for (int i = 0; i < 16; ++i) {
                a0 += bf2f(g[i] & 0xffffu);
                a1 += bf2f(g[i] >> 16);
            }
#pragma unroll
            for (int i = 0; i < 16; ++i) sa[i] = sb[i];
            e += 16;
        }
    }
    for (; e + 4 <= end; e += 4) {
        int s[4];
#pragma unroll
        for (int i = 0; i < 4; ++i) s[i] = csr[e + i];
        unsigned int g[4];
#pragma unroll
        for (int i = 0; i < 4; ++i) g[i] = M[(unsigned)s[i] * 64u + lane];
#pragma unroll
        for (int i = 0; i < 4; ++i) {
            a0 += bf2f(g[i] & 0xffffu);
            a1 += bf2f(g[i] >> 16);
        }
    }
    for (; e < end; ++e) {
        unsigned int gs = M[(unsigned)csr[e] * 64u + lane];
        a0 += bf2f(gs & 0xffffu);
        a1 += bf2f(gs >> 16);
    }

    float di = dinv[row];
    int c0 = lane * 2;
    float v0 = fmaxf(a0 * di * sc[c0] + sh[c0], 0.f);
    float v1 = fmaxf(a1 * di * sc[c0 + 1] + sh[c0 + 1], 0.f);
    H[(unsigned)row * 64u + lane] = bf16r(v0) | (bf16r(v1) << 16);
}

// ---------------- pooling ----------------
__global__ __launch_bounds__(64) void pool1(const unsigned int* __restrict__ H,
                                            const int* __restrict__ gstart,
                                            float4* __restrict__ pbuf) {
    int g = blockIdx.x, c = blockIdx.y;
    int lane = threadIdx.x;
    int beg = gstart[g], end = gstart[g + 1];
    int len = end - beg;
    int cb = beg + (int)(((long long)len * c) >> 3);
    int ce = beg + (int)(((long long)len * (c + 1)) >> 3);
    float s0 = 0.f, s1 = 0.f, m0 = -INFINITY, m1 = -INFINITY;
    int i = cb;
    for (; i + 2 <= ce; i += 2) {
        unsigned int ua = H[(size_t)i * 64 + lane];
        unsigned int ub = H[(size_t)(i + 1) * 64 + lane];
        float a0 = bf2f(ua & 0xffffu), a1 = bf2f(ua >> 16);
        float b0 = bf2f(ub & 0xffffu), b1 = bf2f(ub >> 16);
        s0 += a0 + b0; s1 += a1 + b1;
        m0 = fmaxf(m0, fmaxf(a0, b0)); m1 = fmaxf(m1, fmaxf(a1, b1));
    }
    for (; i < ce; ++i) {
        unsigned int ua = H[(size_t)i * 64 + lane];
        float a0 = bf2f(ua & 0xffffu), a1 = bf2f(ua >> 16);
        s0 += a0; s1 += a1;
        m0 = fmaxf(m0, a0); m1 = fmaxf(m1, a1);
    }
    pbuf[((size_t)g * 8 + c) * 64 + lane] = make_float4(s0, s1, m0, m1);
}

__global__ __launch_bounds__(64) void pool2(const float4* __restrict__ pbuf,
                                            const int* __restrict__ gstart,
                                            float* __restrict__ out) {
    int g = blockIdx.x;
    int lane = threadIdx.x;
    float s0 = 0.f, s1 = 0.f, m0 = -INFINITY, m1 = -INFINITY;
#pragma unroll
    for (int c = 0; c < 8; ++c) {
        float4 p = pbuf[((size_t)g * 8 + c) * 64 + lane];
        s0 += p.x; s1 += p.y;
        m0 = fmaxf(m0, p.z); m1 = fmaxf(m1, p.w);
    }
    float cnt = fmaxf((float)(gstart[g + 1] - gstart[g]), 1.0f);
    int c0 = lane * 2;
    out[g * (2 * D) + c0] = s0 / cnt;
    out[g * (2 * D) + c0 + 1] = s1 / cnt;
    out[g * (2 * D) + D + c0] = m0;
    out[g * (2 * D) + D + c0 + 1] = m1;
}

// ---------------- launch ----------------
extern "C" void kernel_launch(void* const* d_in, const int* in_sizes, int n_in,
                              void* d_out, int out_size, void* d_ws, size_t ws_size,
                              hipStream_t stream) {
    const float* x     = (const float*)d_in[0];
    const float* W     = (const float*)d_in[1];
    const float* b     = (const float*)d_in[2];
    const float* gamma = (const float*)d_in[3];
    const float* beta  = (const float*)d_in[4];
    const float* rmean = (const float*)d_in[5];
    const float* rvar  = (const float*)d_in[6];
    const int*   eidx  = (const int*)d_in[7];
    const int*   batch = (const int*)d_in[8];

    const int N = in_sizes[8];
    const int E = in_sizes[7] / 2;
    const int L = in_sizes[2] / D;
    const int G = out_size / (2 * D);

    const int* esrc = eidx;
    const int* edst = eidx + E;

    size_t off = 0;
    auto carve = [&](size_t bytes) { size_t cur = off; off += (bytes + 255) & ~(size_t)255; return cur; };
    char* base = (char*)d_ws;
    const int nb = (N + 1023) / 1024;

    int*            cnt  = (int*)           (base + carve((size_t)N * 4));
    int*            rp   = (int*)           (base + carve((size_t)(N + 1) * 4));
    int*            aux  = (int*)           (base + carve((size_t)nb * 4));
    float*          dinv = (float*)         (base + carve((size_t)N * 4));
    int*            rank = (int*)           (base + carve((size_t)E * 4));
    int*            csr  = (int*)           (base + carve((size_t)E * 4));
    unsigned short* hbuf = (unsigned short*)(base + carve((size_t)N * D * 2));
    unsigned short* mbuf = (unsigned short*)(base + carve((size_t)N * D * 2));
    unsigned short* Wt   = (unsigned short*)(base + carve((size_t)L * D * D * 2));
    float*          sc   = (float*)         (base + carve((size_t)L * D * 4));
    float*          shb  = (float*)         (base + carve((size_t)L * D * 4));
    int*            gst  = (int*)           (base + carve((size_t)(G + 1) * 4));
    float4*         pbuf = (float4*)        (base + carve((size_t)G * 8 * 64 * 16));
    (void)ws_size;

    hipMemsetAsync(cnt, 0, (size_t)N * 4, stream);

    const int cb = ((E + 3) / 4 + 255) / 256;          // count blocks
    const int wb = (L * D * D + 255) / 256;            // wprep blocks
    const int bb = (N + 255) / 256;                    // bounds blocks
    const int gemmb = (N + GBM - 1) / GBM;
    const int fb = ((E + 3) / 4 + 511) / 512;          // fill blocks (512 thr)
    const int aggb = (N + 3) / 4;

    prep_fused<<<cb + wb + bb, 256, 0, stream>>>(edst, cnt, rank, E,
                                                 W, b, gamma, beta, rmean, rvar,
                                                 Wt, sc, shb, L,
                                                 batch, gst, N, G, cb, wb);
    scan1<<<nb, 256, 0, stream>>>(cnt, rp, aux, dinv, N);
    scan2<<<1, 256, 0, stream>>>(aux, nb);

    fused_fill_gemm0<<<gemmb + fb, 512, 0, stream>>>(x, Wt, dinv, mbuf, N,
                                                     esrc, edst, rp, aux, rank, csr, E, gemmb);
    agg_bf16<<<aggb, 256, 0, stream>>>((const unsigned int*)mbuf, rp, aux, csr, dinv,
                                       sc, shb, (unsigned int*)hbuf, N, E);

    for (int l = 1; l < L; ++l) {
        gemm_mfma<<<gemmb, 512, 0, stream>>>(hbuf, Wt + (size_t)l * D * D, dinv, mbuf, N);
        agg_bf16<<<aggb, 256, 0, stream>>>((const unsigned int*)mbuf, rp, aux, csr, dinv,
                                           sc + l * D, shb + l * D,
                                           (unsigned int*)hbuf, N, E);
    }

    pool1<<<dim3(G, 8), 64, 0, stream>>>((const unsigned int*)hbuf, gst, pbuf);
    pool2<<<G, 64, 0, stream>>>(pbuf, gst, (float*)d_out);
}

// Round 16
// 362.093 us; speedup vs baseline: 1.0372x; 1.0137x over previous
//
#include <hip/hip_runtime.h>
#include <math.h>
#include <float.h>

#define D 128

typedef short short8 __attribute__((ext_vector_type(8)));
typedef float f32x4 __attribute__((ext_vector_type(4)));

__device__ __forceinline__ unsigned int bf16r(float f) {
    unsigned int u = __float_as_uint(f);
    return (u + 0x7fffu + ((u >> 16) & 1u)) >> 16;   // RNE
}
__device__ __forceinline__ float bf2f(unsigned int lo16) {
    return __uint_as_float(lo16 << 16);
}

// ---------------- fused prep: count_rank | wprep | bounds ----------------
// R11-proven: only LOW-TRAFFIC work rides free under the atomic wall
// (R13/R14 falsified heavy-traffic riders: atomics + memory traffic share
// fabric transaction capacity).
__global__ __launch_bounds__(256) void prep_fused(
    const int* __restrict__ dst, int* __restrict__ cnt, int* __restrict__ rank, int E,
    const float* __restrict__ W, const float* __restrict__ b,
    const float* __restrict__ gamma, const float* __restrict__ beta,
    const float* __restrict__ rmean, const float* __restrict__ rvar,
    unsigned short* __restrict__ Wt, float* __restrict__ sc, float* __restrict__ sh, int L_,
    const int* __restrict__ batch, int* __restrict__ gstart, int n, int G,
    int cb, int wb) {
    int blk = blockIdx.x;
    int tid = threadIdx.x;
    if (blk < cb) {
        // ---- count + rank (batch-4) ----
        int base = (blk * 256 + tid) * 4;
        if (base + 4 <= E) {
            int4 d = *(const int4*)&dst[base];
            int r0 = atomicAdd(&cnt[d.x], 1);
            int r1 = atomicAdd(&cnt[d.y], 1);
            int r2 = atomicAdd(&cnt[d.z], 1);
            int r3 = atomicAdd(&cnt[d.w], 1);
            *(int4*)&rank[base] = make_int4(r0, r1, r2, r3);
        } else if (base < E) {
            for (int e = base; e < E; ++e) rank[e] = atomicAdd(&cnt[dst[e]], 1);
        }
    } else if (blk < cb + wb) {
        // ---- wprep: W transpose -> bf16, BN fold ----
        int t = (blk - cb) * 256 + tid;
        int total = L_ * D * D;
        if (t < total) {
            int l = t / (D * D), rem = t % (D * D);
            int r = rem >> 7, k = rem & 127;          // Wt[l][r][k] = W[l][k][r]
            Wt[t] = (unsigned short)bf16r(W[l * D * D + k * D + r]);
        }
        if (t < L_ * D) {
            float inv = rsqrtf(rvar[t] + 1e-5f);
            float s = inv * gamma[t];
            sc[t] = s;
            sh[t] = (b[t] - rmean[t]) * s + beta[t];
        }
    } else {
        // ---- bounds: graph start offsets from sorted batch ----
        int i = (blk - cb - wb) * 256 + tid;
        if (i >= n) return;
        int g = batch[i];
        int gp = (i == 0) ? -1 : batch[i - 1];
        for (int gg = gp + 1; gg <= g; ++gg) gstart[gg] = i;
        if (i == n - 1) for (int gg = g + 1; gg <= G; ++gg) gstart[gg] = n;
    }
}

// ---------------- scans (block-local exclusive; consumers add aux[idx>>10]) ----------------

__global__ void scan1(const int* __restrict__ cnt, int* __restrict__ rp, int* __restrict__ aux,
                      float* __restrict__ dinv, int n) {
    __shared__ int sh[256];
    int tid = threadIdx.x;
    int base = blockIdx.x * 1024 + tid * 4;
    int v[4]; int s = 0;
#pragma unroll
    for (int i = 0; i < 4; i++) {
        int idx = base + i;
        int t = (idx < n) ? cnt[idx] : 0;
        if (idx < n) dinv[idx] = rsqrtf((float)t + 1.0f);   // +1 self-loop
        v[i] = s; s += t;
    }
    sh[tid] = s; __syncthreads();
    for (int off = 1; off < 256; off <<= 1) {
        int t = (tid >= off) ? sh[tid - off] : 0;
        __syncthreads();
        sh[tid] += t;
        __syncthreads();
    }
    int excl = sh[tid] - s;
#pragma unroll
    for (int i = 0; i < 4; i++) { int idx = base + i; if (idx < n) rp[idx] = excl + v[i]; }
    if (tid == 255) aux[blockIdx.x] = sh[255];
}

__global__ void scan2(int* aux, int nb) {
    __shared__ int sh[256];
    int tid = threadIdx.x;
    int v = (tid < nb) ? aux[tid] : 0;
    sh[tid] = v; __syncthreads();
    for (int off = 1; off < 256; off <<= 1) {
        int t = (tid >= off) ? sh[tid - off] : 0;
        __syncthreads();
        sh[tid] += t;
        __syncthreads();
    }
    if (tid < nb) aux[tid] = sh[tid] - v;   // exclusive
}

// ---------------- gemm0 body (no A-tile LDS: each wave reads its own rows) ----------------
#define GBM 128
__device__ __forceinline__ void gemm0_body(short* Wl, const float* __restrict__ x,
                                           const unsigned short* __restrict__ Wt,
                                           const float* __restrict__ dinv,
                                           unsigned short* __restrict__ mout, int n, int blk) {
    const int tid = threadIdx.x;
    const int row0 = blk * GBM;

    // stage Wt (128x128 bf16): 2048 chunks of 8 bf16
#pragma unroll
    for (int i = 0; i < 4; ++i) {
        int c = tid + i * 512;
        int r = c >> 4, ck = (c & 15) * 8;
        *(int4*)&Wl[r * 136 + ck] = *(const int4*)&Wt[(size_t)r * D + ck];
    }
    __syncthreads();

    const int wid = tid >> 6;          // wave 0..7 -> nodes [wid*16, wid*16+16)
    const int lane = tid & 63;
    const int lr = lane & 15;
    const int lg = lane >> 4;

    const int grow = row0 + wid * 16 + lr;
    const bool valid = grow < n;

    f32x4 acc[8];
#pragma unroll
    for (int fc = 0; fc < 8; ++fc) acc[fc] = (f32x4){0.f, 0.f, 0.f, 0.f};

#pragma unroll
    for (int ks = 0; ks < 4; ++ks) {
        int kb = ks * 32 + lg * 8;
        float4 va = make_float4(0.f, 0.f, 0.f, 0.f);
        float4 vb = make_float4(0.f, 0.f, 0.f, 0.f);
        if (valid) {
            va = *(const float4*)&x[(size_t)grow * D + kb];
            vb = *(const float4*)&x[(size_t)grow * D + kb + 4];
        }
        uint4 pk;
        pk.x = bf16r(va.x) | (bf16r(va.y) << 16);
        pk.y = bf16r(va.z) | (bf16r(va.w) << 16);
        pk.z = bf16r(vb.x) | (bf16r(vb.y) << 16);
        pk.w = bf16r(vb.z) | (bf16r(vb.w) << 16);
        short8 y = *(short8*)&pk;
#pragma unroll
        for (int fc = 0; fc < 8; ++fc) {
            short8 xf = *(const short8*)&Wl[(fc * 16 + lr) * 136 + kb];
            acc[fc] = __builtin_amdgcn_mfma_f32_16x16x32_bf16(xf, y, acc[fc], 0, 0, 0);
        }
    }

    if (valid) {
        float di = dinv[grow];
#pragma unroll
        for (int fc = 0; fc < 8; ++fc) {
            int gcol = fc * 16 + lg * 4;
            uint2 pk;
            pk.x = bf16r(acc[fc][0] * di) | (bf16r(acc[fc][1] * di) << 16);
            pk.y = bf16r(acc[fc][2] * di) | (bf16r(acc[fc][3] * di) << 16);
            *(uint2*)&mout[(size_t)grow * D + gcol] = pk;
        }
    }
}

// ---------------- fused: fill | gemm0 ----------------
// fill is latency-bound (VALUBusy 0.6%) -> gemm0's MFMA work hides under it (R11-proven).
__global__ __launch_bounds__(512) void fused_fill_gemm0(
    const float* __restrict__ x, const unsigned short* __restrict__ Wt,
    const float* __restrict__ dinv, unsigned short* __restrict__ mout, int n,
    const int* __restrict__ src, const int* __restrict__ dst,
    const int* __restrict__ rp, const int* __restrict__ aux,
    const int* __restrict__ rank, int* __restrict__ csr, int E, int gemmb) {
    __shared__ short Wl[D * 136];
    if ((int)blockIdx.x < gemmb) {
        gemm0_body(Wl, x, Wt, dinv, mout, n, blockIdx.x);
    } else {
        int gblk = blockIdx.x - gemmb;
        int base = (gblk * 512 + (int)threadIdx.x) * 4;
        if (base + 4 <= E) {
            int4 d = *(const int4*)&dst[base];
            int4 s = *(const int4*)&src[base];
            int4 r = *(const int4*)&rank[base];
            int p0 = rp[d.x] + aux[d.x >> 10];
            int p1 = rp[d.y] + aux[d.y >> 10];
            int p2 = rp[d.z] + aux[d.z >> 10];
            int p3 = rp[d.w] + aux[d.w >> 10];
            csr[p0 + r.x] = s.x;
            csr[p1 + r.y] = s.y;
            csr[p2 + r.z] = s.z;
            csr[p3 + r.w] = s.w;
        } else if (base < E) {
            for (int e = base; e < E; ++e)
                csr[rp[dst[e]] + aux[dst[e] >> 10] + rank[e]] = src[e];
        }
    }
}

// ---------------- staged-W GEMM, no A-tile LDS (layers 1,2) ----------------
// A rows have zero cross-wave reuse: each row is consumed by exactly one wave,
// so LDS-staging A was pure overhead (32KB write+read) AND halved occupancy
// (68KB -> 2 blocks/CU). Direct per-lane global reads: 16 aligned 64B lines
// per wave instruction (full utilization, R11 gemm0_body precedent).
__global__ __launch_bounds__(512) void gemm_mfma(const unsigned short* __restrict__ hin,
                                                 const unsigned short* __restrict__ Wt,
                                                 const float* __restrict__ dinv,
                                                 unsigned short* __restrict__ mout, int n) {
    __shared__ short Wl[D * 136];
    const int tid = threadIdx.x;
    const int row0 = blockIdx.x * GBM;

#pragma unroll
    for (int i = 0; i < 4; ++i) {
        int c = tid + i * 512;
        int r = c >> 4, ck = (c & 15) * 8;
        *(int4*)&Wl[r * 136 + ck] = *(const int4*)&Wt[(size_t)r * D + ck];
    }
    __syncthreads();

    const int wid = tid >> 6;
    const int lane = tid & 63;
    const int lr = lane & 15;
    const int lg = lane >> 4;

    const int grow = row0 + wid * 16 + lr;
    const bool valid = grow < n;

    f32x4 acc[8];
#pragma unroll
    for (int fc = 0; fc < 8; ++fc) acc[fc] = (f32x4){0.f, 0.f, 0.f, 0.f};

#pragma unroll
    for (int ks = 0; ks < 4; ++ks) {
        int kb = ks * 32 + lg * 8;
        short8 y;
        if (valid) y = *(const short8*)&hin[(size_t)grow * D + kb];
        else { int4 z = make_int4(0, 0, 0, 0); y = *(short8*)&z; }
#pragma unroll
        for (int fc = 0; fc < 8; ++fc) {
            short8 xf = *(const short8*)&Wl[(fc * 16 + lr) * 136 + kb];
            acc[fc] = __builtin_amdgcn_mfma_f32_16x16x32_bf16(xf, y, acc[fc], 0, 0, 0);
        }
    }

    if (valid) {
        float di = dinv[grow];
#pragma unroll
        for (int fc = 0; fc < 8; ++fc) {
            int gcol = fc * 16 + lg * 4;
            uint2 pk;
            pk.x = bf16r(acc[fc][0] * di) | (bf16r(acc[fc][1] * di) << 16);
            pk.y = bf16r(acc[fc][2] * di) | (bf16r(acc[fc][3] * di) << 16);
            *(uint2*)&mout[(size_t)grow * D + gcol] = pk;
        }
    }
}

// ---------------- fused aggregation + bias + BN + ReLU (bf16 in/out, f32 acc) ----------------
__global__ __launch_bounds__(256) void agg_bf16(const unsigned int* __restrict__ M,
                                                const int* __restrict__ rp,
                                                const int* __restrict__ aux,
                                                const int* __restrict__ csr,
                                                const float* __restrict__ dinv,
                                                const float* __restrict__ sc,
                                                const float* __restrict__ sh,
                                                unsigned int* __restrict__ H, int n, int Etot) {
    const int wid = threadIdx.x >> 6;
    const int lane = threadIdx.x & 63;
    const int row = blockIdx.x * 4 + wid;
    if (row >= n) return;

    unsigned int u = M[(unsigned)row * 64u + lane];
    float a0 = bf2f(u & 0xffffu);
    float a1 = bf2f(u >> 16);

    int e = rp[row] + aux[row >> 10];
    const int end = (row + 1 < n) ? rp[row + 1] + aux[(row + 1) >> 10] : Etot;
    const int n16 = (end - e) >> 4;

    if (n16 > 0) {
        int sa[16];
#pragma unroll
        for (int i = 0; i < 16; ++i) sa[i] = csr[e + i];
        for (int it = 0; it < n16; ++it) {
            int sb[16];
            if (it + 1 < n16) {
#pragma unroll
                for (int i = 0; i < 16; ++i) sb[i] = csr[e + 16 + i];
            } else {
#pragma unroll
                for (int i = 0; i < 16; ++i) sb[i] = 0;
            }
            unsigned int g[16];
#pragma unroll
            for (int i = 0; i < 16; ++i) g[i] = M[(unsigned)sa[i] * 64u + lane];
#pragma unroll
            for (int i = 0; i < 16; ++i) {
                a0 += bf2f(g[i] & 0xffffu);
                a1 += bf2f(g[i] >> 16);
            }
#pragma unroll
            for (int i = 0; i < 16; ++i) sa[i] = sb[i];
            e += 16;
        }
    }
    for (; e + 4 <= end; e += 4) {
        int s[4];
#pragma unroll
        for (int i = 0; i < 4; ++i) s[i] = csr[e + i];
        unsigned int g[4];
#pragma unroll
        for (int i = 0; i < 4; ++i) g[i] = M[(unsigned)s[i] * 64u + lane];
#pragma unroll
        for (int i = 0; i < 4; ++i) {
            a0 += bf2f(g[i] & 0xffffu);
            a1 += bf2f(g[i] >> 16);
        }
    }
    for (; e < end; ++e) {
        unsigned int gs = M[(unsigned)csr[e] * 64u + lane];
        a0 += bf2f(gs & 0xffffu);
        a1 += bf2f(gs >> 16);
    }

    float di = dinv[row];
    int c0 = lane * 2;
    float v0 = fmaxf(a0 * di * sc[c0] + sh[c0], 0.f);
    float v1 = fmaxf(a1 * di * sc[c0 + 1] + sh[c0 + 1], 0.f);
    H[(unsigned)row * 64u + lane] = bf16r(v0) | (bf16r(v1) << 16);
}

// ---------------- pooling ----------------
__global__ __launch_bounds__(64) void pool1(const unsigned int* __restrict__ H,
                                            const int* __restrict__ gstart,
                                            float4* __restrict__ pbuf) {
    int g = blockIdx.x, c = blockIdx.y;
    int lane = threadIdx.x;
    int beg = gstart[g], end = gstart[g + 1];
    int len = end - beg;
    int cb = beg + (int)(((long long)len * c) >> 3);
    int ce = beg + (int)(((long long)len * (c + 1)) >> 3);
    float s0 = 0.f, s1 = 0.f, m0 = -INFINITY, m1 = -INFINITY;
    int i = cb;
    for (; i + 2 <= ce; i += 2) {
        unsigned int ua = H[(size_t)i * 64 + lane];
        unsigned int ub = H[(size_t)(i + 1) * 64 + lane];
        float a0 = bf2f(ua & 0xffffu), a1 = bf2f(ua >> 16);
        float b0 = bf2f(ub & 0xffffu), b1 = bf2f(ub >> 16);
        s0 += a0 + b0; s1 += a1 + b1;
        m0 = fmaxf(m0, fmaxf(a0, b0)); m1 = fmaxf(m1, fmaxf(a1, b1));
    }
    for (; i < ce; ++i) {
        unsigned int ua = H[(size_t)i * 64 + lane];
        float a0 = bf2f(ua & 0xffffu), a1 = bf2f(ua >> 16);
        s0 += a0; s1 += a1;
        m0 = fmaxf(m0, a0); m1 = fmaxf(m1, a1);
    }
    pbuf[((size_t)g * 8 + c) * 64 + lane] = make_float4(s0, s1, m0, m1);
}

__global__ __launch_bounds__(64) void pool2(const float4* __restrict__ pbuf,
                                            const int* __restrict__ gstart,
                                            float* __restrict__ out) {
    int g = blockIdx.x;
    int lane = threadIdx.x;
    float s0 = 0.f, s1 = 0.f, m0 = -INFINITY, m1 = -INFINITY;
#pragma unroll
    for (int c = 0; c < 8; ++c) {
        float4 p = pbuf[((size_t)g * 8 + c) * 64 + lane];
        s0 += p.x; s1 += p.y;
        m0 = fmaxf(m0, p.z); m1 = fmaxf(m1, p.w);
    }
    float cnt = fmaxf((float)(gstart[g + 1] - gstart[g]), 1.0f);
    int c0 = lane * 2;
    out[g * (2 * D) + c0] = s0 / cnt;
    out[g * (2 * D) + c0 + 1] = s1 / cnt;
    out[g * (2 * D) + D + c0] = m0;
    out[g * (2 * D) + D + c0 + 1] = m1;
}

// ---------------- launch ----------------
extern "C" void kernel_launch(void* const* d_in, const int* in_sizes, int n_in,
                              void* d_out, int out_size, void* d_ws, size_t ws_size,
                              hipStream_t stream) {
    const float* x     = (const float*)d_in[0];
    const float* W     = (const float*)d_in[1];
    const float* b     = (const float*)d_in[2];
    const float* gamma = (const float*)d_in[3];
    const float* beta  = (const float*)d_in[4];
    const float* rmean = (const float*)d_in[5];
    const float* rvar  = (const float*)d_in[6];
    const int*   eidx  = (const int*)d_in[7];
    const int*   batch = (const int*)d_in[8];

    const int N = in_sizes[8];
    const int E = in_sizes[7] / 2;
    const int L = in_sizes[2] / D;
    const int G = out_size / (2 * D);

    const int* esrc = eidx;
    const int* edst = eidx + E;

    size_t off = 0;
    auto carve = [&](size_t bytes) { size_t cur = off; off += (bytes + 255) & ~(size_t)255; return cur; };
    char* base = (char*)d_ws;
    const int nb = (N + 1023) / 1024;

    int*            cnt  = (int*)           (base + carve((size_t)N * 4));
    int*            rp   = (int*)           (base + carve((size_t)(N + 1) * 4));
    int*            aux  = (int*)           (base + carve((size_t)nb * 4));
    float*          dinv = (float*)         (base + carve((size_t)N * 4));
    int*            rank = (int*)           (base + carve((size_t)E * 4));
    int*            csr  = (int*)           (base + carve((size_t)E * 4));
    unsigned short* hbuf = (unsigned short*)(base + carve((size_t)N * D * 2));
    unsigned short* mbuf = (unsigned short*)(base + carve((size_t)N * D * 2));
    unsigned short* Wt   = (unsigned short*)(base + carve((size_t)L * D * D * 2));
    float*          sc   = (float*)         (base + carve((size_t)L * D * 4));
    float*          shb  = (float*)         (base + carve((size_t)L * D * 4));
    int*            gst  = (int*)           (base + carve((size_t)(G + 1) * 4));
    float4*         pbuf = (float4*)        (base + carve((size_t)G * 8 * 64 * 16));
    (void)ws_size;

    hipMemsetAsync(cnt, 0, (size_t)N * 4, stream);

    const int cb = ((E + 3) / 4 + 255) / 256;          // count blocks
    const int wb = (L * D * D + 255) / 256;            // wprep blocks
    const int bb = (N + 255) / 256;                    // bounds blocks
    const int gemmb = (N + GBM - 1) / GBM;
    const int fb = ((E + 3) / 4 + 511) / 512;          // fill blocks (512 thr)
    const int aggb = (N + 3) / 4;

    prep_fused<<<cb + wb + bb, 256, 0, stream>>>(edst, cnt, rank, E,
                                                 W, b, gamma, beta, rmean, rvar,
                                                 Wt, sc, shb, L,
                                                 batch, gst, N, G, cb, wb);
    scan1<<<nb, 256, 0, stream>>>(cnt, rp, aux, dinv, N);
    scan2<<<1, 256, 0, stream>>>(aux, nb);

    fused_fill_gemm0<<<gemmb + fb, 512, 0, stream>>>(x, Wt, dinv, mbuf, N,
                                                     esrc, edst, rp, aux, rank, csr, E, gemmb);
    agg_bf16<<<aggb, 256, 0, stream>>>((const unsigned int*)mbuf, rp, aux, csr, dinv,
                                       sc, shb, (unsigned int*)hbuf, N, E);

    for (int l = 1; l < L; ++l) {
        gemm_mfma<<<gemmb, 512, 0, stream>>>(hbuf, Wt + (size_t)l * D * D, dinv, mbuf, N);
        agg_bf16<<<aggb, 256, 0, stream>>>((const unsigned int*)mbuf, rp, aux, csr, dinv,
                                           sc + l * D, shb + l * D,
                                           (unsigned int*)hbuf, N, E);
    }

    pool1<<<dim3(G, 8), 64, 0, stream>>>((const unsigned int*)hbuf, gst, pbuf);
    pool2<<<G, 64, 0, stream>>>(pbuf, gst, (float*)d_out);
}

// Round 17
// 346.161 us; speedup vs baseline: 1.0850x; 1.0460x over previous
//
#include <hip/hip_runtime.h>
#include <math.h>
#include <float.h>

#define D 128

typedef short short8 __attribute__((ext_vector_type(8)));
typedef float f32x4 __attribute__((ext_vector_type(4)));

__device__ __forceinline__ unsigned int bf16r(float f) {
    unsigned int u = __float_as_uint(f);
    return (u + 0x7fffu + ((u >> 16) & 1u)) >> 16;   // RNE
}
__device__ __forceinline__ float bf2f(unsigned int lo16) {
    return __uint_as_float(lo16 << 16);
}

// ---------------- fused prep: count_rank | wprep | bounds ----------------
__global__ __launch_bounds__(256) void prep_fused(
    const int* __restrict__ dst, int* __restrict__ cnt, int* __restrict__ rank, int E,
    const float* __restrict__ W, const float* __restrict__ b,
    const float* __restrict__ gamma, const float* __restrict__ beta,
    const float* __restrict__ rmean, const float* __restrict__ rvar,
    unsigned short* __restrict__ Wt, float* __restrict__ sc, float* __restrict__ sh, int L_,
    const int* __restrict__ batch, int* __restrict__ gstart, int n, int G,
    int cb, int wb) {
    int blk = blockIdx.x;
    int tid = threadIdx.x;
    if (blk < cb) {
        int base = (blk * 256 + tid) * 4;
        if (base + 4 <= E) {
            int4 d = *(const int4*)&dst[base];
            int r0 = atomicAdd(&cnt[d.x], 1);
            int r1 = atomicAdd(&cnt[d.y], 1);
            int r2 = atomicAdd(&cnt[d.z], 1);
            int r3 = atomicAdd(&cnt[d.w], 1);
            *(int4*)&rank[base] = make_int4(r0, r1, r2, r3);
        } else if (base < E) {
            for (int e = base; e < E; ++e) rank[e] = atomicAdd(&cnt[dst[e]], 1);
        }
    } else if (blk < cb + wb) {
        int t = (blk - cb) * 256 + tid;
        int total = L_ * D * D;
        if (t < total) {
            int l = t / (D * D), rem = t % (D * D);
            int r = rem >> 7, k = rem & 127;          // Wt[l][r][k] = W[l][k][r]
            Wt[t] = (unsigned short)bf16r(W[l * D * D + k * D + r]);
        }
        if (t < L_ * D) {
            float inv = rsqrtf(rvar[t] + 1e-5f);
            float s = inv * gamma[t];
            sc[t] = s;
            sh[t] = (b[t] - rmean[t]) * s + beta[t];
        }
    } else {
        int i = (blk - cb - wb) * 256 + tid;
        if (i >= n) return;
        int g = batch[i];
        int gp = (i == 0) ? -1 : batch[i - 1];
        for (int gg = gp + 1; gg <= g; ++gg) gstart[gg] = i;
        if (i == n - 1) for (int gg = g + 1; gg <= G; ++gg) gstart[gg] = n;
    }
}

// ---------------- scans (block-local exclusive; consumers add aux[idx>>10]) ----------------

__global__ void scan1(const int* __restrict__ cnt, int* __restrict__ rp, int* __restrict__ aux,
                      float* __restrict__ dinv, int n) {
    __shared__ int sh[256];
    int tid = threadIdx.x;
    int base = blockIdx.x * 1024 + tid * 4;
    int v[4]; int s = 0;
#pragma unroll
    for (int i = 0; i < 4; i++) {
        int idx = base + i;
        int t = (idx < n) ? cnt[idx] : 0;
        if (idx < n) dinv[idx] = rsqrtf((float)t + 1.0f);   // +1 self-loop
        v[i] = s; s += t;
    }
    sh[tid] = s; __syncthreads();
    for (int off = 1; off < 256; off <<= 1) {
        int t = (tid >= off) ? sh[tid - off] : 0;
        __syncthreads();
        sh[tid] += t;
        __syncthreads();
    }
    int excl = sh[tid] - s;
#pragma unroll
    for (int i = 0; i < 4; i++) { int idx = base + i; if (idx < n) rp[idx] = excl + v[i]; }
    if (tid == 255) aux[blockIdx.x] = sh[255];
}

__global__ void scan2(int* aux, int nb) {
    __shared__ int sh[256];
    int tid = threadIdx.x;
    int v = (tid < nb) ? aux[tid] : 0;
    sh[tid] = v; __syncthreads();
    for (int off = 1; off < 256; off <<= 1) {
        int t = (tid >= off) ? sh[tid - off] : 0;
        __syncthreads();
        sh[tid] += t;
        __syncthreads();
    }
    if (tid < nb) aux[tid] = sh[tid] - v;   // exclusive
}

// ---------------- gemm0 body (no A-tile LDS) ----------------
#define GBM 128
__device__ __forceinline__ void gemm0_body(short* Wl, const float* __restrict__ x,
                                           const unsigned short* __restrict__ Wt,
                                           const float* __restrict__ dinv,
                                           unsigned short* __restrict__ mout, int n, int blk) {
    const int tid = threadIdx.x;
    const int row0 = blk * GBM;

#pragma unroll
    for (int i = 0; i < 4; ++i) {
        int c = tid + i * 512;
        int r = c >> 4, ck = (c & 15) * 8;
        *(int4*)&Wl[r * 136 + ck] = *(const int4*)&Wt[(size_t)r * D + ck];
    }
    __syncthreads();

    const int wid = tid >> 6;
    const int lane = tid & 63;
    const int lr = lane & 15;
    const int lg = lane >> 4;

    const int grow = row0 + wid * 16 + lr;
    const bool valid = grow < n;

    f32x4 acc[8];
#pragma unroll
    for (int fc = 0; fc < 8; ++fc) acc[fc] = (f32x4){0.f, 0.f, 0.f, 0.f};

#pragma unroll
    for (int ks = 0; ks < 4; ++ks) {
        int kb = ks * 32 + lg * 8;
        float4 va = make_float4(0.f, 0.f, 0.f, 0.f);
        float4 vb = make_float4(0.f, 0.f, 0.f, 0.f);
        if (valid) {
            va = *(const float4*)&x[(size_t)grow * D + kb];
            vb = *(const float4*)&x[(size_t)grow * D + kb + 4];
        }
        uint4 pk;
        pk.x = bf16r(va.x) | (bf16r(va.y) << 16);
        pk.y = bf16r(va.z) | (bf16r(va.w) << 16);
        pk.z = bf16r(vb.x) | (bf16r(vb.y) << 16);
        pk.w = bf16r(vb.z) | (bf16r(vb.w) << 16);
        short8 y = *(short8*)&pk;
#pragma unroll
        for (int fc = 0; fc < 8; ++fc) {
            short8 xf = *(const short8*)&Wl[(fc * 16 + lr) * 136 + kb];
            acc[fc] = __builtin_amdgcn_mfma_f32_16x16x32_bf16(xf, y, acc[fc], 0, 0, 0);
        }
    }

    if (valid) {
        float di = dinv[grow];
#pragma unroll
        for (int fc = 0; fc < 8; ++fc) {
            int gcol = fc * 16 + lg * 4;
            uint2 pk;
            pk.x = bf16r(acc[fc][0] * di) | (bf16r(acc[fc][1] * di) << 16);
            pk.y = bf16r(acc[fc][2] * di) | (bf16r(acc[fc][3] * di) << 16);
            *(uint2*)&mout[(size_t)grow * D + gcol] = pk;
        }
    }
}

// ---------------- fused: fill | gemm0 ----------------
__global__ __launch_bounds__(512) void fused_fill_gemm0(
    const float* __restrict__ x, const unsigned short* __restrict__ Wt,
    const float* __restrict__ dinv, unsigned short* __restrict__ mout, int n,
    const int* __restrict__ src, const int* __restrict__ dst,
    const int* __restrict__ rp, const int* __restrict__ aux,
    const int* __restrict__ rank, int* __restrict__ csr, int E, int gemmb) {
    __shared__ short Wl[D * 136];
    if ((int)blockIdx.x < gemmb) {
        gemm0_body(Wl, x, Wt, dinv, mout, n, blockIdx.x);
    } else {
        int gblk = blockIdx.x - gemmb;
        int base = (gblk * 512 + (int)threadIdx.x) * 4;
        if (base + 4 <= E) {
            int4 d = *(const int4*)&dst[base];
            int4 s = *(const int4*)&src[base];
            int4 r = *(const int4*)&rank[base];
            int p0 = rp[d.x] + aux[d.x >> 10];
            int p1 = rp[d.y] + aux[d.y >> 10];
            int p2 = rp[d.z] + aux[d.z >> 10];
            int p3 = rp[d.w] + aux[d.w >> 10];
            csr[p0 + r.x] = s.x;
            csr[p1 + r.y] = s.y;
            csr[p2 + r.z] = s.z;
            csr[p3 + r.w] = s.w;
        } else if (base < E) {
            for (int e = base; e < E; ++e)
                csr[rp[dst[e]] + aux[dst[e] >> 10] + rank[e]] = src[e];
        }
    }
}

// ---------------- agg inner: returns (a0,a1) = self + sum of gathered src rows ----------------
__device__ __forceinline__ void agg_row(const unsigned int* __restrict__ M,
                                        const int* __restrict__ rp,
                                        const int* __restrict__ aux,
                                        const int* __restrict__ csr,
                                        int row, int n, int Etot, int lane,
                                        float& a0, float& a1) {
    unsigned int u = M[(unsigned)row * 64u + lane];
    a0 = bf2f(u & 0xffffu);
    a1 = bf2f(u >> 16);

    int e = rp[row] + aux[row >> 10];
    const int end = (row + 1 < n) ? rp[row + 1] + aux[(row + 1) >> 10] : Etot;
    const int n16 = (end - e) >> 4;

    if (n16 > 0) {
        int sa[16];
#pragma unroll
        for (int i = 0; i < 16; ++i) sa[i] = csr[e + i];
        for (int it = 0; it < n16; ++it) {
            int sb[16];
            if (it + 1 < n16) {
#pragma unroll
                for (int i = 0; i < 16; ++i) sb[i] = csr[e + 16 + i];
            } else {
#pragma unroll
                for (int i = 0; i < 16; ++i) sb[i] = 0;
            }
            unsigned int g[16];
#pragma unroll
            for (int i = 0; i < 16; ++i) g[i] = M[(unsigned)sa[i] * 64u + lane];
#pragma unroll
            for (int i = 0; i < 16; ++i) {
                a0 += bf2f(g[i] & 0xffffu);
                a1 += bf2f(g[i] >> 16);
            }
#pragma unroll
            for (int i = 0; i < 16; ++i) sa[i] = sb[i];
            e += 16;
        }
    }
    for (; e + 4 <= end; e += 4) {
        int s[4];
#pragma unroll
        for (int i = 0; i < 4; ++i) s[i] = csr[e + i];
        unsigned int g[4];
#pragma unroll
        for (int i = 0; i < 4; ++i) g[i] = M[(unsigned)s[i] * 64u + lane];
#pragma unroll
        for (int i = 0; i < 4; ++i) {
            a0 += bf2f(g[i] & 0xffffu);
            a1 += bf2f(g[i] >> 16);
        }
    }
    for (; e < end; ++e) {
        unsigned int gs = M[(unsigned)csr[e] * 64u + lane];
        a0 += bf2f(gs & 0xffffu);
        a1 += bf2f(gs >> 16);
    }
}

// ---------------- fused agg + next-layer GEMM (transitions 0->1, 1->2) ----------------
// Persistent blocks: stage Wt(l+1) once; grid-stride over 16-row tiles:
// agg 16 rows (2/wave) -> h in LDS (never touches global) -> one 16-feature
// MFMA tile per wave -> write m(l+1)*dinv. Saves h write+read (52MB/transition).
__global__ __launch_bounds__(512) void agg_gemm(
    const unsigned int* __restrict__ M,
    const int* __restrict__ rp, const int* __restrict__ aux,
    const int* __restrict__ csr, const float* __restrict__ dinv,
    const float* __restrict__ sc, const float* __restrict__ sh,
    const unsigned short* __restrict__ Wt,
    unsigned short* __restrict__ mout, int n, int Etot, int ntiles) {
    __shared__ short Wl[D * 136];
    __shared__ short Hl[16 * 136];
    const int tid = threadIdx.x;

    // stage Wt(l+1) once
#pragma unroll
    for (int i = 0; i < 4; ++i) {
        int c = tid + i * 512;
        int r = c >> 4, ck = (c & 15) * 8;
        *(int4*)&Wl[r * 136 + ck] = *(const int4*)&Wt[(size_t)r * D + ck];
    }

    const int wid = tid >> 6;
    const int lane = tid & 63;
    const int lr = lane & 15;
    const int lg = lane >> 4;
    const int c0 = lane * 2;
    const float s0v = sc[c0], s1v = sc[c0 + 1];
    const float h0v = sh[c0], h1v = sh[c0 + 1];

    __syncthreads();

    for (int tile = blockIdx.x; tile < ntiles; tile += gridDim.x) {
        const int row0 = tile * 16;
        // ---- agg phase: each wave computes 2 rows ----
#pragma unroll
        for (int rr = 0; rr < 2; ++rr) {
            int rloc = wid * 2 + rr;
            int row = row0 + rloc;
            unsigned int hv = 0;
            if (row < n) {
                float a0, a1;
                agg_row(M, rp, aux, csr, row, n, Etot, lane, a0, a1);
                float di = dinv[row];
                float v0 = fmaxf(a0 * di * s0v + h0v, 0.f);
                float v1 = fmaxf(a1 * di * s1v + h1v, 0.f);
                hv = bf16r(v0) | (bf16r(v1) << 16);
            }
            *(unsigned int*)&Hl[rloc * 136 + lane * 2] = hv;
        }
        __syncthreads();

        // ---- MFMA phase: wave w -> features [w*16, w*16+16) for the 16 nodes ----
        f32x4 acc = (f32x4){0.f, 0.f, 0.f, 0.f};
#pragma unroll
        for (int ks = 0; ks < 4; ++ks) {
            int kb = ks * 32 + lg * 8;
            short8 y = *(const short8*)&Hl[lr * 136 + kb];
            short8 xf = *(const short8*)&Wl[(wid * 16 + lr) * 136 + kb];
            acc = __builtin_amdgcn_mfma_f32_16x16x32_bf16(xf, y, acc, 0, 0, 0);
        }
        int node = row0 + lr;
        if (node < n) {
            float di = dinv[node];
            uint2 pk;
            pk.x = bf16r(acc[0] * di) | (bf16r(acc[1] * di) << 16);
            pk.y = bf16r(acc[2] * di) | (bf16r(acc[3] * di) << 16);
            *(uint2*)&mout[(size_t)node * D + wid * 16 + lg * 4] = pk;
        }
        __syncthreads();   // protect Hl before next tile overwrites
    }
}

// ---------------- final aggregation + bias + BN + ReLU (layer L-1) ----------------
__global__ __launch_bounds__(256) void agg_bf16(const unsigned int* __restrict__ M,
                                                const int* __restrict__ rp,
                                                const int* __restrict__ aux,
                                                const int* __restrict__ csr,
                                                const float* __restrict__ dinv,
                                                const float* __restrict__ sc,
                                                const float* __restrict__ sh,
                                                unsigned int* __restrict__ H, int n, int Etot) {
    const int wid = threadIdx.x >> 6;
    const int lane = threadIdx.x & 63;
    const int row = blockIdx.x * 4 + wid;
    if (row >= n) return;

    float a0, a1;
    agg_row(M, rp, aux, csr, row, n, Etot, lane, a0, a1);

    float di = dinv[row];
    int c0 = lane * 2;
    float v0 = fmaxf(a0 * di * sc[c0] + sh[c0], 0.f);
    float v1 = fmaxf(a1 * di * sc[c0 + 1] + sh[c0 + 1], 0.f);
    H[(unsigned)row * 64u + lane] = bf16r(v0) | (bf16r(v1) << 16);
}

// ---------------- pooling ----------------
__global__ __launch_bounds__(64) void pool1(const unsigned int* __restrict__ H,
                                            const int* __restrict__ gstart,
                                            float4* __restrict__ pbuf) {
    int g = blockIdx.x, c = blockIdx.y;
    int lane = threadIdx.x;
    int beg = gstart[g], end = gstart[g + 1];
    int len = end - beg;
    int cb = beg + (int)(((long long)len * c) >> 3);
    int ce = beg + (int)(((long long)len * (c + 1)) >> 3);
    float s0 = 0.f, s1 = 0.f, m0 = -INFINITY, m1 = -INFINITY;
    int i = cb;
    for (; i + 2 <= ce; i += 2) {
        unsigned int ua = H[(size_t)i * 64 + lane];
        unsigned int ub = H[(size_t)(i + 1) * 64 + lane];
        float a0 = bf2f(ua & 0xffffu), a1 = bf2f(ua >> 16);
        float b0 = bf2f(ub & 0xffffu), b1 = bf2f(ub >> 16);
        s0 += a0 + b0; s1 += a1 + b1;
        m0 = fmaxf(m0, fmaxf(a0, b0)); m1 = fmaxf(m1, fmaxf(a1, b1));
    }
    for (; i < ce; ++i) {
        unsigned int ua = H[(size_t)i * 64 + lane];
        float a0 = bf2f(ua & 0xffffu), a1 = bf2f(ua >> 16);
        s0 += a0; s1 += a1;
        m0 = fmaxf(m0, a0); m1 = fmaxf(m1, a1);
    }
    pbuf[((size_t)g * 8 + c) * 64 + lane] = make_float4(s0, s1, m0, m1);
}

__global__ __launch_bounds__(64) void pool2(const float4* __restrict__ pbuf,
                                            const int* __restrict__ gstart,
                                            float* __restrict__ out) {
    int g = blockIdx.x;
    int lane = threadIdx.x;
    float s0 = 0.f, s1 = 0.f, m0 = -INFINITY, m1 = -INFINITY;
#pragma unroll
    for (int c = 0; c < 8; ++c) {
        float4 p = pbuf[((size_t)g * 8 + c) * 64 + lane];
        s0 += p.x; s1 += p.y;
        m0 = fmaxf(m0, p.z); m1 = fmaxf(m1, p.w);
    }
    float cnt = fmaxf((float)(gstart[g + 1] - gstart[g]), 1.0f);
    int c0 = lane * 2;
    out[g * (2 * D) + c0] = s0 / cnt;
    out[g * (2 * D) + c0 + 1] = s1 / cnt;
    out[g * (2 * D) + D + c0] = m0;
    out[g * (2 * D) + D + c0 + 1] = m1;
}

// ---------------- launch ----------------
extern "C" void kernel_launch(void* const* d_in, const int* in_sizes, int n_in,
                              void* d_out, int out_size, void* d_ws, size_t ws_size,
                              hipStream_t stream) {
    const float* x     = (const float*)d_in[0];
    const float* W     = (const float*)d_in[1];
    const float* b     = (const float*)d_in[2];
    const float* gamma = (const float*)d_in[3];
    const float* beta  = (const float*)d_in[4];
    const float* rmean = (const float*)d_in[5];
    const float* rvar  = (const float*)d_in[6];
    const int*   eidx  = (const int*)d_in[7];
    const int*   batch = (const int*)d_in[8];

    const int N = in_sizes[8];
    const int E = in_sizes[7] / 2;
    const int L = in_sizes[2] / D;
    const int G = out_size / (2 * D);

    const int* esrc = eidx;
    const int* edst = eidx + E;

    size_t off = 0;
    auto carve = [&](size_t bytes) { size_t cur = off; off += (bytes + 255) & ~(size_t)255; return cur; };
    char* base = (char*)d_ws;
    const int nb = (N + 1023) / 1024;

    int*            cnt  = (int*)           (base + carve((size_t)N * 4));
    int*            rp   = (int*)           (base + carve((size_t)(N + 1) * 4));
    int*            aux  = (int*)           (base + carve((size_t)nb * 4));
    float*          dinv = (float*)         (base + carve((size_t)N * 4));
    int*            rank = (int*)           (base + carve((size_t)E * 4));
    int*            csr  = (int*)           (base + carve((size_t)E * 4));
    unsigned short* bufA = (unsigned short*)(base + carve((size_t)N * D * 2));
    unsigned short* bufB = (unsigned short*)(base + carve((size_t)N * D * 2));
    unsigned short* Wt   = (unsigned short*)(base + carve((size_t)L * D * D * 2));
    float*          sc   = (float*)         (base + carve((size_t)L * D * 4));
    float*          shb  = (float*)         (base + carve((size_t)L * D * 4));
    int*            gst  = (int*)           (base + carve((size_t)(G + 1) * 4));
    float4*         pbuf = (float4*)        (base + carve((size_t)G * 8 * 64 * 16));
    (void)ws_size;

    hipMemsetAsync(cnt, 0, (size_t)N * 4, stream);

    const int cb = ((E + 3) / 4 + 255) / 256;          // count blocks
    const int wb = (L * D * D + 255) / 256;            // wprep blocks
    const int bb = (N + 255) / 256;                    // bounds blocks
    const int gemmb = (N + GBM - 1) / GBM;
    const int fb = ((E + 3) / 4 + 511) / 512;          // fill blocks (512 thr)
    const int aggb = (N + 3) / 4;
    const int ntiles = (N + 15) / 16;
    const int agblocks = ntiles < 1024 ? ntiles : 1024;

    prep_fused<<<cb + wb + bb, 256, 0, stream>>>(edst, cnt, rank, E,
                                                 W, b, gamma, beta, rmean, rvar,
                                                 Wt, sc, shb, L,
                                                 batch, gst, N, G, cb, wb);
    scan1<<<nb, 256, 0, stream>>>(cnt, rp, aux, dinv, N);
    scan2<<<1, 256, 0, stream>>>(aux, nb);

    // m0' -> bufA (gemm0 fused with fill)
    fused_fill_gemm0<<<gemmb + fb, 512, 0, stream>>>(x, Wt, dinv, bufA, N,
                                                     esrc, edst, rp, aux, rank, csr, E, gemmb);

    // transition 0->1: agg(m0') + gemm(W1) -> m1' in bufB
    agg_gemm<<<agblocks, 512, 0, stream>>>((const unsigned int*)bufA, rp, aux, csr, dinv,
                                           sc, shb, Wt + (size_t)1 * D * D,
                                           bufB, N, E, ntiles);
    // transition 1->2: agg(m1') + gemm(W2) -> m2' in bufA
    agg_gemm<<<agblocks, 512, 0, stream>>>((const unsigned int*)bufB, rp, aux, csr, dinv,
                                           sc + D, shb + D, Wt + (size_t)2 * D * D,
                                           bufA, N, E, ntiles);
    // final: agg(m2') -> h2 in bufB
    agg_bf16<<<aggb, 256, 0, stream>>>((const unsigned int*)bufA, rp, aux, csr, dinv,
                                       sc + 2 * D, shb + 2 * D,
                                       (unsigned int*)bufB, N, E);

    pool1<<<dim3(G, 8), 64, 0, stream>>>((const unsigned int*)bufB, gst, pbuf);
    pool2<<<G, 64, 0, stream>>>(pbuf, gst, (float*)d_out);
}